// Round 1
// baseline (1309.329 us; speedup 1.0000x reference)
//
#include <hip/hip_runtime.h>

// ---------------------------------------------------------------------------
// RGCN: h = relu( mean-agg per (dst,rel) of x[src] @ W[rel] + x @ root + b )
// Restructured: aggregate x[src] FIRST (in_ch wide), then one GEMM
//   A = [Sn_rel0 | Sn_rel1 | x_self]  (K = 3*in),  Wcat = [W0; W1; root]
// CSR built once per call (deg histogram -> scan -> scatter), reused 3 layers.
// ---------------------------------------------------------------------------

__device__ __forceinline__ void fma4(float4& a, float s, const float4& w){
  a.x += s*w.x; a.y += s*w.y; a.z += s*w.z; a.w += s*w.w;
}

__global__ __launch_bounds__(256) void k_hist(const int* __restrict__ ei,
    const int* __restrict__ et, int* __restrict__ deg, int E){
  int e = blockIdx.x*256 + threadIdx.x;
  if (e < E){
    int dst = ei[E + e];           // edge_index row 1
    int ty  = et[e];
    atomicAdd(&deg[dst*2 + ty], 1);
  }
}

// exclusive scan of deg[M] -> pos[M], hierarchical (2048 elems / block)
__global__ __launch_bounds__(256) void k_scan1(const int* __restrict__ deg,
    int* __restrict__ pos, int* __restrict__ bsum, int M){
  __shared__ int lds[256];
  int t = threadIdx.x;
  int base = blockIdx.x*2048 + t*8;
  int v[8]; int s = 0;
  #pragma unroll
  for (int j=0;j<8;++j){ int idx=base+j; v[j] = (idx<M)? deg[idx]:0; s += v[j]; }
  lds[t] = s; __syncthreads();
  for (int off=1; off<256; off<<=1){
    int tmp = (t>=off)? lds[t-off]:0;
    __syncthreads();
    lds[t] += tmp;
    __syncthreads();
  }
  int incl = lds[t];
  int excl = incl - s;
  if (t==255) bsum[blockIdx.x] = incl;
  int run = excl;
  #pragma unroll
  for (int j=0;j<8;++j){ int idx=base+j; if (idx<M) pos[idx]=run; run+=v[j]; }
}

__global__ __launch_bounds__(256) void k_scan2(int* __restrict__ bsum, int NB){
  __shared__ int lds[256];
  int t = threadIdx.x;
  int val = (t<NB)? bsum[t]:0;
  lds[t]=val; __syncthreads();
  for (int off=1; off<256; off<<=1){
    int tmp=(t>=off)? lds[t-off]:0;
    __syncthreads();
    lds[t]+=tmp;
    __syncthreads();
  }
  if (t<NB) bsum[t] = lds[t]-val;   // exclusive
}

__global__ __launch_bounds__(256) void k_scan3(int* __restrict__ pos,
    const int* __restrict__ bsum, int M){
  int t = threadIdx.x;
  int base = blockIdx.x*2048 + t*8;
  int add = bsum[blockIdx.x];
  #pragma unroll
  for (int j=0;j<8;++j){ int idx=base+j; if (idx<M) pos[idx]+=add; }
}

// scatter src ids into CSR order; pos[] mutates to segment END (start = pos-deg)
__global__ __launch_bounds__(256) void k_scatter(const int* __restrict__ ei,
    const int* __restrict__ et, int* __restrict__ pos, int* __restrict__ ssrc, int E){
  int e = blockIdx.x*256 + threadIdx.x;
  if (e<E){
    int src = ei[e], dst = ei[E+e], ty = et[e];
    int p = atomicAdd(&pos[dst*2+ty], 1);
    ssrc[p] = src;
  }
}

// wave-per-node gather: lane = channel (64 wide). srcs broadcast via shfl.
__device__ __forceinline__ float gather64(const float* __restrict__ hp,
    const int* __restrict__ ssrc, int off, int cnt, int lane){
  float s = 0.f;
  while (cnt > 0){
    int take = cnt < 64 ? cnt : 64;
    int sv = (lane < take) ? ssrc[off + lane] : 0;
    int e = 0;
    for (; e+3 < take; e += 4){      // 4-deep ILP on the random gathers
      int i0=__shfl(sv,e), i1=__shfl(sv,e+1), i2=__shfl(sv,e+2), i3=__shfl(sv,e+3);
      float f0=hp[i0*64+lane], f1=hp[i1*64+lane], f2=hp[i2*64+lane], f3=hp[i3*64+lane];
      s += f0; s += f1; s += f2; s += f3;
    }
    for (; e<take; ++e){ int i0=__shfl(sv,e); s += hp[i0*64+lane]; }
    off += take; cnt -= take;
  }
  return s;
}

// layers 2/3: in=64, K=192. LDS A-tile stride 193 (==1 mod 32: conflict-free).
template<int RELU>
__global__ __launch_bounds__(256) void k_layer64(
    const float* __restrict__ hp, const int* __restrict__ deg,
    const int* __restrict__ pos, const int* __restrict__ ssrc,
    const float* __restrict__ Wl,    // [128,64] = [W_r0; W_r1]
    const float* __restrict__ rootp, // [64,64]
    const float* __restrict__ bias, float* __restrict__ hout, int N)
{
  __shared__ float A[64*193];
  int t = threadIdx.x, lane = t&63, wv = t>>6;
  int nb = blockIdx.x*64;
  // phase 1: aggregate 16 nodes per wave
  for (int it=0; it<16; ++it){
    int nl = wv*16+it, n = nb+nl;
    float s0=0.f, s1=0.f, xs=0.f;
    if (n<N){
      int d0 = deg[2*n], d1 = deg[2*n+1];
      int p0 = pos[2*n]-d0, p1 = pos[2*n+1]-d1;
      s0 = gather64(hp, ssrc, p0, d0, lane);
      s1 = gather64(hp, ssrc, p1, d1, lane);
      s0 *= 1.f/(float)(d0>1?d0:1);
      s1 *= 1.f/(float)(d1>1?d1:1);
      xs = hp[n*64+lane];
    }
    A[nl*193+lane]=s0; A[nl*193+64+lane]=s1; A[nl*193+128+lane]=xs;
  }
  __syncthreads();
  // phase 2: 4 nodes x 4 outs per thread
  int o0 = (t&15)*4, r0 = (t>>4)*4;
  float4 b4 = *(const float4*)(bias+o0);
  float4 a0=b4,a1=b4,a2=b4,a3=b4;
  const float* Ab = &A[r0*193];
  #pragma unroll 4
  for (int i=0;i<128;++i){
    float4 w = *(const float4*)(Wl + i*64 + o0);
    fma4(a0, Ab[i],     w); fma4(a1, Ab[193+i], w);
    fma4(a2, Ab[386+i], w); fma4(a3, Ab[579+i], w);
  }
  #pragma unroll 4
  for (int i=0;i<64;++i){
    float4 w = *(const float4*)(rootp + i*64 + o0);
    fma4(a0, Ab[128+i], w); fma4(a1, Ab[321+i], w);
    fma4(a2, Ab[514+i], w); fma4(a3, Ab[707+i], w);
  }
  float4 accs[4] = {a0,a1,a2,a3};
  #pragma unroll
  for (int q=0;q<4;++q){
    int n = nb + r0 + q;
    if (n < N){
      float4 r = accs[q];
      if (RELU){ r.x=fmaxf(r.x,0.f); r.y=fmaxf(r.y,0.f); r.z=fmaxf(r.z,0.f); r.w=fmaxf(r.w,0.f); }
      *(float4*)(hout + n*64 + o0) = r;
    }
  }
}

// layer 1 gather: 8 edges x 8 channels per wave, xor-reduce over edge groups
__device__ __forceinline__ float gather8(const float* __restrict__ xp,
    const int* __restrict__ ssrc, int off, int cnt, int lane){
  float s = 0.f;
  int c = lane & 7, eg = lane >> 3;
  while (cnt > 0){
    int take = cnt < 64 ? cnt : 64;
    int sv = (lane < take) ? ssrc[off + lane] : 0;
    for (int e=0; e<take; e+=8){
      int idx = e + eg;                 // <= 63 always
      int si = __shfl(sv, idx);
      float v = (idx < take) ? xp[si*8 + c] : 0.f;
      s += v;
    }
    off += take; cnt -= take;
  }
  s += __shfl_xor(s, 8);
  s += __shfl_xor(s, 16);
  s += __shfl_xor(s, 32);
  return s;                             // every lane: sum for channel lane&7
}

__global__ __launch_bounds__(256) void k_layer1(
    const float* __restrict__ xp, const int* __restrict__ deg,
    const int* __restrict__ pos, const int* __restrict__ ssrc,
    const float* __restrict__ Wl,    // [16,64]
    const float* __restrict__ rootp, // [8,64]
    const float* __restrict__ bias, float* __restrict__ hout, int N)
{
  __shared__ float A[64*25];
  int t=threadIdx.x, lane=t&63, wv=t>>6;
  int nb=blockIdx.x*64;
  for (int it=0; it<16; ++it){
    int nl=wv*16+it, n=nb+nl;
    float s0=0.f,s1=0.f,xs=0.f;
    if (n<N){
      int d0=deg[2*n], d1=deg[2*n+1];
      int p0=pos[2*n]-d0, p1=pos[2*n+1]-d1;
      s0=gather8(xp,ssrc,p0,d0,lane);
      s1=gather8(xp,ssrc,p1,d1,lane);
      s0 *= 1.f/(float)(d0>1?d0:1);
      s1 *= 1.f/(float)(d1>1?d1:1);
      if (lane < 8) xs = xp[n*8 + lane];
    }
    if (lane < 8){
      A[nl*25+lane]=s0; A[nl*25+8+lane]=s1; A[nl*25+16+lane]=xs;
    }
  }
  __syncthreads();
  int o0=(t&15)*4, r0=(t>>4)*4;
  float4 b4 = *(const float4*)(bias+o0);
  float4 a0=b4,a1=b4,a2=b4,a3=b4;
  const float* Ab=&A[r0*25];
  #pragma unroll
  for (int i=0;i<16;++i){
    float4 w=*(const float4*)(Wl+i*64+o0);
    fma4(a0,Ab[i],w); fma4(a1,Ab[25+i],w); fma4(a2,Ab[50+i],w); fma4(a3,Ab[75+i],w);
  }
  #pragma unroll
  for (int i=0;i<8;++i){
    float4 w=*(const float4*)(rootp+i*64+o0);
    fma4(a0,Ab[16+i],w); fma4(a1,Ab[41+i],w); fma4(a2,Ab[66+i],w); fma4(a3,Ab[91+i],w);
  }
  float4 accs[4]={a0,a1,a2,a3};
  #pragma unroll
  for (int q=0;q<4;++q){
    int n = nb + r0 + q;
    if (n < N){
      float4 r = accs[q];
      r.x=fmaxf(r.x,0.f); r.y=fmaxf(r.y,0.f); r.z=fmaxf(r.z,0.f); r.w=fmaxf(r.w,0.f);
      *(float4*)(hout + n*64 + o0) = r;
    }
  }
}

__device__ __forceinline__ int lowerb(const int* __restrict__ b, int n, int key){
  int lo=0, hi=n;
  while (lo<hi){ int mid=(lo+hi)>>1; if (b[mid]<key) lo=mid+1; else hi=mid; }
  return lo;
}

// batch is sorted: block g sums its contiguous node range
__global__ __launch_bounds__(256) void k_pool(const float* __restrict__ h,
    const int* __restrict__ batch, float* __restrict__ gp, int N){
  __shared__ float red[256];
  int g=blockIdx.x, t=threadIdx.x;
  int start=lowerb(batch,N,g), end=lowerb(batch,N,g+1);
  int c=t&63, p=t>>6;
  float s=0.f;
  for (int n=start+p; n<end; n+=4) s += h[n*64+c];
  red[t]=s; __syncthreads();
  if (t<64) gp[g*64+c] = red[c]+red[64+c]+red[128+c]+red[192+c];
}

__global__ __launch_bounds__(256) void k_clf(const float* __restrict__ gp,
    const float* __restrict__ cW1, const float* __restrict__ cb1,
    const float* __restrict__ cW2, const float* __restrict__ cb2,
    float* __restrict__ out, int G){
  int t=threadIdx.x;
  if (t<G){
    float gv[64];
    #pragma unroll
    for (int i=0;i<64;++i) gv[i]=gp[t*64+i];
    float o=cb2[0];
    for (int j=0;j<32;++j){
      float h=cb1[j];
      #pragma unroll 8
      for (int i=0;i<64;++i) h += gv[i]*cW1[i*32+j];
      o += fmaxf(h,0.f)*cW2[j];
    }
    out[t]=o;
  }
}

extern "C" void kernel_launch(void* const* d_in, const int* in_sizes, int n_in,
                              void* d_out, int out_size, void* d_ws, size_t ws_size,
                              hipStream_t stream){
  const float* x     = (const float*)d_in[0];
  const int*   ei    = (const int*)d_in[1];
  const int*   et    = (const int*)d_in[2];
  const int*   batch = (const int*)d_in[3];
  const float* W1    = (const float*)d_in[4];
  const float* root1 = (const float*)d_in[5];
  const float* b1    = (const float*)d_in[6];
  const float* W2    = (const float*)d_in[7];
  const float* root2 = (const float*)d_in[8];
  const float* b2    = (const float*)d_in[9];
  const float* W3    = (const float*)d_in[10];
  const float* root3 = (const float*)d_in[11];
  const float* b3    = (const float*)d_in[12];
  const float* cW1   = (const float*)d_in[13];
  const float* cb1   = (const float*)d_in[14];
  const float* cW2   = (const float*)d_in[15];
  const float* cb2   = (const float*)d_in[16];
  float* out = (float*)d_out;
  (void)n_in; (void)ws_size;

  int N = in_sizes[0]/8;      // 100000
  int E = in_sizes[2];        // 3200000
  int G = out_size;           // 256
  int M = 2*N;

  char* w = (char*)d_ws;
  auto alloc=[&](size_t bytes)->char*{ char* p=w; w += (bytes+255)&~(size_t)255; return p; };
  int*   deg  = (int*)alloc((size_t)M*4);
  int*   pos  = (int*)alloc((size_t)M*4);
  int*   bsum = (int*)alloc(256*4);
  int*   ssrc = (int*)alloc((size_t)E*4);
  float* hA   = (float*)alloc((size_t)N*64*4);
  float* hB   = (float*)alloc((size_t)N*64*4);
  float* gp   = (float*)alloc((size_t)G*64*4);

  hipMemsetAsync(deg, 0, (size_t)M*4, stream);
  int eb=(E+255)/256;
  k_hist<<<eb,256,0,stream>>>(ei,et,deg,E);
  int NB=(M+2047)/2048;
  k_scan1<<<NB,256,0,stream>>>(deg,pos,bsum,M);
  k_scan2<<<1,256,0,stream>>>(bsum,NB);
  k_scan3<<<NB,256,0,stream>>>(pos,bsum,M);
  k_scatter<<<eb,256,0,stream>>>(ei,et,pos,ssrc,E);
  int nbk=(N+63)/64;
  k_layer1<<<nbk,256,0,stream>>>(x,deg,pos,ssrc,W1,root1,b1,hA,N);
  k_layer64<1><<<nbk,256,0,stream>>>(hA,deg,pos,ssrc,W2,root2,b2,hB,N);
  k_layer64<0><<<nbk,256,0,stream>>>(hB,deg,pos,ssrc,W3,root3,b3,hA,N);
  k_pool<<<G,256,0,stream>>>(hA,batch,gp,N);
  k_clf<<<1,256,0,stream>>>(gp,cW1,cb1,cW2,cb2,out,G);
}

// Round 2
// 1237.301 us; speedup vs baseline: 1.0582x; 1.0582x over previous
//
#include <hip/hip_runtime.h>

// ---------------------------------------------------------------------------
// RGCN restructured: aggregate x[src] FIRST (per relation), then one GEMM
//   A = [Sn_rel0 | Sn_rel1 | x_self],  Wcat = [W0; W1; root]
// CSR built per call (hist -> scan -> scatter), reused across 3 layers.
// R2: intermediate h stored in bf16 (halves random-gather bytes, the
//     binding constraint = L3 random-read BW); gathers use 8B/lane loads
//     (4 edges per load instruction) + shfl_xor reduction.
// ---------------------------------------------------------------------------

typedef unsigned int uint;
typedef unsigned short ushort;

__device__ __forceinline__ void fma4(float4& a, float s, const float4& w){
  a.x += s*w.x; a.y += s*w.y; a.z += s*w.z; a.w += s*w.w;
}

__device__ __forceinline__ uint bf1(float f){          // f32 -> bf16 (RNE)
  uint u = __float_as_uint(f);
  return (u + 0x7fffu + ((u>>16)&1u)) >> 16;
}
__device__ __forceinline__ uint bfpack2(float lo, float hi){
  return bf1(lo) | (bf1(hi)<<16);
}
__device__ __forceinline__ void bf4acc(uint2 w, float4& s){ // 4 bf16 += into f32x4
  s.x += __uint_as_float(w.x<<16);
  s.y += __uint_as_float(w.x & 0xffff0000u);
  s.z += __uint_as_float(w.y<<16);
  s.w += __uint_as_float(w.y & 0xffff0000u);
}
__device__ __forceinline__ float4 bf4cvt(uint2 w){
  float4 r;
  r.x = __uint_as_float(w.x<<16);
  r.y = __uint_as_float(w.x & 0xffff0000u);
  r.z = __uint_as_float(w.y<<16);
  r.w = __uint_as_float(w.y & 0xffff0000u);
  return r;
}

// ------------------------------ CSR build ---------------------------------

__global__ __launch_bounds__(256) void k_hist(const int* __restrict__ ei,
    const int* __restrict__ et, int* __restrict__ deg, int E){
  int e = blockIdx.x*256 + threadIdx.x;
  if (e < E){
    int dst = ei[E + e];
    int ty  = et[e];
    atomicAdd(&deg[dst*2 + ty], 1);
  }
}

__global__ __launch_bounds__(256) void k_scan1(const int* __restrict__ deg,
    int* __restrict__ pos, int* __restrict__ bsum, int M){
  __shared__ int lds[256];
  int t = threadIdx.x;
  int base = blockIdx.x*2048 + t*8;
  int v[8]; int s = 0;
  #pragma unroll
  for (int j=0;j<8;++j){ int idx=base+j; v[j] = (idx<M)? deg[idx]:0; s += v[j]; }
  lds[t] = s; __syncthreads();
  for (int off=1; off<256; off<<=1){
    int tmp = (t>=off)? lds[t-off]:0;
    __syncthreads();
    lds[t] += tmp;
    __syncthreads();
  }
  int incl = lds[t];
  int excl = incl - s;
  if (t==255) bsum[blockIdx.x] = incl;
  int run = excl;
  #pragma unroll
  for (int j=0;j<8;++j){ int idx=base+j; if (idx<M) pos[idx]=run; run+=v[j]; }
}

__global__ __launch_bounds__(256) void k_scan2(int* __restrict__ bsum, int NB){
  __shared__ int lds[256];
  int t = threadIdx.x;
  int val = (t<NB)? bsum[t]:0;
  lds[t]=val; __syncthreads();
  for (int off=1; off<256; off<<=1){
    int tmp=(t>=off)? lds[t-off]:0;
    __syncthreads();
    lds[t]+=tmp;
    __syncthreads();
  }
  if (t<NB) bsum[t] = lds[t]-val;   // exclusive
}

__global__ __launch_bounds__(256) void k_scan3(int* __restrict__ pos,
    const int* __restrict__ bsum, int M){
  int t = threadIdx.x;
  int base = blockIdx.x*2048 + t*8;
  int add = bsum[blockIdx.x];
  #pragma unroll
  for (int j=0;j<8;++j){ int idx=base+j; if (idx<M) pos[idx]+=add; }
}

// pos[] mutates to segment END (start = pos-deg)
__global__ __launch_bounds__(256) void k_scatter(const int* __restrict__ ei,
    const int* __restrict__ et, int* __restrict__ pos, int* __restrict__ ssrc, int E){
  int e = blockIdx.x*256 + threadIdx.x;
  if (e<E){
    int src = ei[e], dst = ei[E+e], ty = et[e];
    int p = atomicAdd(&pos[dst*2+ty], 1);
    ssrc[p] = src;
  }
}

// --------------------------- layers 2/3 (in=64) ---------------------------
// gather: 16 lanes cover one bf16 row (8 B/lane), 4 edges per load round.
// result valid on lanes 0..15 (c4 = lane&15 -> channels 4*c4..4*c4+3).
__device__ __forceinline__ float4 gather_bf(const ushort* __restrict__ hp,
    const int* __restrict__ ssrc, int off, int cnt, int lane){
  float4 s = {0.f,0.f,0.f,0.f};
  int c4 = lane & 15, eg = lane >> 4;
  while (cnt > 0){
    int take = cnt < 64 ? cnt : 64;
    int sv = (lane < take) ? ssrc[off + lane] : 0;
    #pragma unroll 4
    for (int e = 0; e < take; e += 4){
      int idx = e + eg;
      int si = __shfl(sv, idx);
      uint2 w = {0u,0u};
      if (idx < take) w = *(const uint2*)(hp + si*64 + c4*4);
      bf4acc(w, s);
    }
    off += take; cnt -= take;
  }
  s.x += __shfl_xor(s.x,16); s.x += __shfl_xor(s.x,32);
  s.y += __shfl_xor(s.y,16); s.y += __shfl_xor(s.y,32);
  s.z += __shfl_xor(s.z,16); s.z += __shfl_xor(s.z,32);
  s.w += __shfl_xor(s.w,16); s.w += __shfl_xor(s.w,32);
  return s;
}

#define AST 196   // A-tile stride: 4-aligned (float4 LDS ops), 2-way conflicts only

template<int RELU, int OUTBF>
__global__ __launch_bounds__(256) void k_layer64(
    const ushort* __restrict__ hp, const int* __restrict__ deg,
    const int* __restrict__ pos, const int* __restrict__ ssrc,
    const float* __restrict__ Wl,    // [128,64] = [W_r0; W_r1]
    const float* __restrict__ rootp, // [64,64]
    const float* __restrict__ bias, void* __restrict__ hout_, int N)
{
  __shared__ float A[64*AST];
  int t = threadIdx.x, lane = t&63, wv = t>>6;
  int nb = blockIdx.x*64;
  int c4 = lane & 15;
  // phase 1: 16 nodes per wave
  for (int it=0; it<16; ++it){
    int nl = wv*16+it, n = nb+nl;
    if (n < N){
      int d0 = deg[2*n], d1 = deg[2*n+1];
      int p0 = pos[2*n]-d0, p1 = pos[2*n+1]-d1;
      float4 s0 = gather_bf(hp, ssrc, p0, d0, lane);
      float4 s1 = gather_bf(hp, ssrc, p1, d1, lane);
      if (lane < 16){
        float i0 = 1.f/(float)(d0>1?d0:1), i1 = 1.f/(float)(d1>1?d1:1);
        s0.x*=i0; s0.y*=i0; s0.z*=i0; s0.w*=i0;
        s1.x*=i1; s1.y*=i1; s1.z*=i1; s1.w*=i1;
        uint2 w = *(const uint2*)(hp + n*64 + c4*4);
        float4 xs = bf4cvt(w);
        *(float4*)&A[nl*AST +       c4*4] = s0;
        *(float4*)&A[nl*AST +  64 + c4*4] = s1;
        *(float4*)&A[nl*AST + 128 + c4*4] = xs;
      }
    } else if (lane < 16){
      float4 z = {0.f,0.f,0.f,0.f};
      *(float4*)&A[nl*AST +       c4*4] = z;
      *(float4*)&A[nl*AST +  64 + c4*4] = z;
      *(float4*)&A[nl*AST + 128 + c4*4] = z;
    }
  }
  __syncthreads();
  // phase 2: 4 nodes x 4 outs per thread
  int o0 = (t&15)*4, r0 = (t>>4)*4;
  float4 b4 = *(const float4*)(bias+o0);
  float4 a0=b4,a1=b4,a2=b4,a3=b4;
  const float* Ab = &A[r0*AST];
  #pragma unroll 4
  for (int i=0;i<128;++i){
    float4 w = *(const float4*)(Wl + i*64 + o0);
    fma4(a0, Ab[i],       w); fma4(a1, Ab[AST+i],   w);
    fma4(a2, Ab[2*AST+i], w); fma4(a3, Ab[3*AST+i], w);
  }
  #pragma unroll 4
  for (int i=0;i<64;++i){
    float4 w = *(const float4*)(rootp + i*64 + o0);
    fma4(a0, Ab[128+i],       w); fma4(a1, Ab[AST+128+i],   w);
    fma4(a2, Ab[2*AST+128+i], w); fma4(a3, Ab[3*AST+128+i], w);
  }
  float4 accs[4] = {a0,a1,a2,a3};
  #pragma unroll
  for (int q=0;q<4;++q){
    int n = nb + r0 + q;
    if (n < N){
      float4 r = accs[q];
      if (RELU){ r.x=fmaxf(r.x,0.f); r.y=fmaxf(r.y,0.f); r.z=fmaxf(r.z,0.f); r.w=fmaxf(r.w,0.f); }
      if (OUTBF){
        uint2 p; p.x = bfpack2(r.x,r.y); p.y = bfpack2(r.z,r.w);
        *(uint2*)((ushort*)hout_ + n*64 + o0) = p;
      } else {
        *(float4*)((float*)hout_ + n*64 + o0) = r;
      }
    }
  }
}

// ------------------------------ layer 1 (in=8) ----------------------------
// gather: 4 lanes cover one f32 row (float2/lane), 16 edges per load round.
// result valid on lanes 0..3 (c2 = lane&3 -> channels 2*c2, 2*c2+1).
__device__ __forceinline__ float2 gather_x(const float* __restrict__ xp,
    const int* __restrict__ ssrc, int off, int cnt, int lane){
  float2 s = {0.f,0.f};
  int c2 = lane & 3, eg = lane >> 2;
  while (cnt > 0){
    int take = cnt < 64 ? cnt : 64;
    int sv = (lane < take) ? ssrc[off + lane] : 0;
    #pragma unroll 2
    for (int e = 0; e < take; e += 16){
      int idx = e + eg;
      int si = __shfl(sv, idx);
      float2 v = {0.f,0.f};
      if (idx < take) v = *(const float2*)(xp + si*8 + c2*2);
      s.x += v.x; s.y += v.y;
    }
    off += take; cnt -= take;
  }
  s.x += __shfl_xor(s.x,4);  s.x += __shfl_xor(s.x,8);
  s.x += __shfl_xor(s.x,16); s.x += __shfl_xor(s.x,32);
  s.y += __shfl_xor(s.y,4);  s.y += __shfl_xor(s.y,8);
  s.y += __shfl_xor(s.y,16); s.y += __shfl_xor(s.y,32);
  return s;
}

__global__ __launch_bounds__(256) void k_layer1(
    const float* __restrict__ xp, const int* __restrict__ deg,
    const int* __restrict__ pos, const int* __restrict__ ssrc,
    const float* __restrict__ Wl,    // [16,64]
    const float* __restrict__ rootp, // [8,64]
    const float* __restrict__ bias, ushort* __restrict__ hout, int N)
{
  __shared__ float A[64*25];
  int t=threadIdx.x, lane=t&63, wv=t>>6;
  int nb=blockIdx.x*64;
  int c2 = lane & 3;
  for (int it=0; it<16; ++it){
    int nl=wv*16+it, n=nb+nl;
    if (n<N){
      int d0=deg[2*n], d1=deg[2*n+1];
      int p0=pos[2*n]-d0, p1=pos[2*n+1]-d1;
      float2 s0=gather_x(xp,ssrc,p0,d0,lane);
      float2 s1=gather_x(xp,ssrc,p1,d1,lane);
      if (lane < 4){
        float i0=1.f/(float)(d0>1?d0:1), i1=1.f/(float)(d1>1?d1:1);
        A[nl*25 +    c2*2  ]=s0.x*i0; A[nl*25 +    c2*2+1]=s0.y*i0;
        A[nl*25 + 8+ c2*2  ]=s1.x*i1; A[nl*25 + 8+ c2*2+1]=s1.y*i1;
      }
      if (lane < 8) A[nl*25 + 16 + lane] = xp[n*8 + lane];
    } else if (lane < 24){
      A[nl*25 + lane] = 0.f;
    }
  }
  __syncthreads();
  int o0=(t&15)*4, r0=(t>>4)*4;
  float4 b4 = *(const float4*)(bias+o0);
  float4 a0=b4,a1=b4,a2=b4,a3=b4;
  const float* Ab=&A[r0*25];
  #pragma unroll
  for (int i=0;i<16;++i){
    float4 w=*(const float4*)(Wl+i*64+o0);
    fma4(a0,Ab[i],w); fma4(a1,Ab[25+i],w); fma4(a2,Ab[50+i],w); fma4(a3,Ab[75+i],w);
  }
  #pragma unroll
  for (int i=0;i<8;++i){
    float4 w=*(const float4*)(rootp+i*64+o0);
    fma4(a0,Ab[16+i],w); fma4(a1,Ab[41+i],w); fma4(a2,Ab[66+i],w); fma4(a3,Ab[91+i],w);
  }
  float4 accs[4]={a0,a1,a2,a3};
  #pragma unroll
  for (int q=0;q<4;++q){
    int n = nb + r0 + q;
    if (n < N){
      float4 r = accs[q];
      r.x=fmaxf(r.x,0.f); r.y=fmaxf(r.y,0.f); r.z=fmaxf(r.z,0.f); r.w=fmaxf(r.w,0.f);
      uint2 p; p.x = bfpack2(r.x,r.y); p.y = bfpack2(r.z,r.w);
      *(uint2*)(hout + n*64 + o0) = p;
    }
  }
}

// ------------------------------- pool + MLP -------------------------------

__device__ __forceinline__ int lowerb(const int* __restrict__ b, int n, int key){
  int lo=0, hi=n;
  while (lo<hi){ int mid=(lo+hi)>>1; if (b[mid]<key) lo=mid+1; else hi=mid; }
  return lo;
}

__global__ __launch_bounds__(256) void k_pool(const float* __restrict__ h,
    const int* __restrict__ batch, float* __restrict__ gp, int N){
  __shared__ float red[256];
  int g=blockIdx.x, t=threadIdx.x;
  int start=lowerb(batch,N,g), end=lowerb(batch,N,g+1);
  int c=t&63, p=t>>6;
  float s=0.f;
  for (int n=start+p; n<end; n+=4) s += h[n*64+c];
  red[t]=s; __syncthreads();
  if (t<64) gp[g*64+c] = red[c]+red[64+c]+red[128+c]+red[192+c];
}

__global__ __launch_bounds__(256) void k_clf(const float* __restrict__ gp,
    const float* __restrict__ cW1, const float* __restrict__ cb1,
    const float* __restrict__ cW2, const float* __restrict__ cb2,
    float* __restrict__ out, int G){
  int t=threadIdx.x;
  if (t<G){
    float gv[64];
    #pragma unroll
    for (int i=0;i<64;++i) gv[i]=gp[t*64+i];
    float o=cb2[0];
    for (int j=0;j<32;++j){
      float h=cb1[j];
      #pragma unroll 8
      for (int i=0;i<64;++i) h += gv[i]*cW1[i*32+j];
      o += fmaxf(h,0.f)*cW2[j];
    }
    out[t]=o;
  }
}

extern "C" void kernel_launch(void* const* d_in, const int* in_sizes, int n_in,
                              void* d_out, int out_size, void* d_ws, size_t ws_size,
                              hipStream_t stream){
  const float* x     = (const float*)d_in[0];
  const int*   ei    = (const int*)d_in[1];
  const int*   et    = (const int*)d_in[2];
  const int*   batch = (const int*)d_in[3];
  const float* W1    = (const float*)d_in[4];
  const float* root1 = (const float*)d_in[5];
  const float* b1    = (const float*)d_in[6];
  const float* W2    = (const float*)d_in[7];
  const float* root2 = (const float*)d_in[8];
  const float* b2    = (const float*)d_in[9];
  const float* W3    = (const float*)d_in[10];
  const float* root3 = (const float*)d_in[11];
  const float* b3    = (const float*)d_in[12];
  const float* cW1   = (const float*)d_in[13];
  const float* cb1   = (const float*)d_in[14];
  const float* cW2   = (const float*)d_in[15];
  const float* cb2   = (const float*)d_in[16];
  float* out = (float*)d_out;
  (void)n_in; (void)ws_size;

  int N = in_sizes[0]/8;      // 100000
  int E = in_sizes[2];        // 3200000
  int G = out_size;           // 256
  int M = 2*N;

  char* w = (char*)d_ws;
  auto alloc=[&](size_t bytes)->char*{ char* p=w; w += (bytes+255)&~(size_t)255; return p; };
  int*    deg  = (int*)alloc((size_t)M*4);
  int*    pos  = (int*)alloc((size_t)M*4);
  int*    bsum = (int*)alloc(256*4);
  int*    ssrc = (int*)alloc((size_t)E*4);
  ushort* hbA  = (ushort*)alloc((size_t)N*64*2);
  ushort* hbB  = (ushort*)alloc((size_t)N*64*2);
  float*  hf   = (float*)alloc((size_t)N*64*4);
  float*  gp   = (float*)alloc((size_t)G*64*4);

  hipMemsetAsync(deg, 0, (size_t)M*4, stream);
  int eb=(E+255)/256;
  k_hist<<<eb,256,0,stream>>>(ei,et,deg,E);
  int NB=(M+2047)/2048;
  k_scan1<<<NB,256,0,stream>>>(deg,pos,bsum,M);
  k_scan2<<<1,256,0,stream>>>(bsum,NB);
  k_scan3<<<NB,256,0,stream>>>(pos,bsum,M);
  k_scatter<<<eb,256,0,stream>>>(ei,et,pos,ssrc,E);
  int nbk=(N+63)/64;
  k_layer1<<<nbk,256,0,stream>>>(x,deg,pos,ssrc,W1,root1,b1,hbA,N);
  k_layer64<1,1><<<nbk,256,0,stream>>>(hbA,deg,pos,ssrc,W2,root2,b2,hbB,N);
  k_layer64<0,0><<<nbk,256,0,stream>>>(hbB,deg,pos,ssrc,W3,root3,b3,hf,N);
  k_pool<<<G,256,0,stream>>>(hf,batch,gp,N);
  k_clf<<<1,256,0,stream>>>(gp,cW1,cb1,cW2,cb2,out,G);
}

// Round 3
// 841.314 us; speedup vs baseline: 1.5563x; 1.4707x over previous
//
#include <hip/hip_runtime.h>

// ---------------------------------------------------------------------------
// RGCN restructured: aggregate x[src] FIRST (per relation), then one GEMM
//   A = [Sn_rel0 | Sn_rel1 | x_self],  Wcat = [W0; W1; root]
// R3: gather split into its own LDS-free kernel at full occupancy
//     (latency-bound random reads scale with wave count), dual-node +
//     merged-relation edge stream for ILP. GEMM kernels read the gathered
//     Sn with coalesced loads; proven conflict-free phase-2 unchanged.
// ---------------------------------------------------------------------------

typedef unsigned int uint;
typedef unsigned short ushort;

__device__ __forceinline__ void fma4(float4& a, float s, const float4& w){
  a.x += s*w.x; a.y += s*w.y; a.z += s*w.z; a.w += s*w.w;
}
__device__ __forceinline__ uint bf1(float f){          // f32 -> bf16 (RNE)
  uint u = __float_as_uint(f);
  return (u + 0x7fffu + ((u>>16)&1u)) >> 16;
}
__device__ __forceinline__ uint bfpack2(float lo, float hi){
  return bf1(lo) | (bf1(hi)<<16);
}
__device__ __forceinline__ float4 bf4cvt(uint2 w){
  float4 r;
  r.x = __uint_as_float(w.x<<16);
  r.y = __uint_as_float(w.x & 0xffff0000u);
  r.z = __uint_as_float(w.y<<16);
  r.w = __uint_as_float(w.y & 0xffff0000u);
  return r;
}
__device__ __forceinline__ float2 bf2cvt(uint w){
  float2 r; r.x = __uint_as_float(w<<16); r.y = __uint_as_float(w & 0xffff0000u);
  return r;
}
__device__ __forceinline__ void redf4(float4& a){
  a.x += __shfl_xor(a.x,16); a.x += __shfl_xor(a.x,32);
  a.y += __shfl_xor(a.y,16); a.y += __shfl_xor(a.y,32);
  a.z += __shfl_xor(a.z,16); a.z += __shfl_xor(a.z,32);
  a.w += __shfl_xor(a.w,16); a.w += __shfl_xor(a.w,32);
}
__device__ __forceinline__ void accsel(float4& s0, float4& s1, float4 f, bool is0){
  s0.x += is0 ? f.x : 0.f;  s1.x += is0 ? 0.f : f.x;
  s0.y += is0 ? f.y : 0.f;  s1.y += is0 ? 0.f : f.y;
  s0.z += is0 ? f.z : 0.f;  s1.z += is0 ? 0.f : f.z;
  s0.w += is0 ? f.w : 0.f;  s1.w += is0 ? 0.f : f.w;
}

// ------------------------------ CSR build ---------------------------------

__global__ __launch_bounds__(256) void k_hist(const int* __restrict__ ei,
    const int* __restrict__ et, int* __restrict__ deg, int E){
  int e = blockIdx.x*256 + threadIdx.x;
  if (e < E){
    int dst = ei[E + e];
    int ty  = et[e];
    atomicAdd(&deg[dst*2 + ty], 1);
  }
}

__global__ __launch_bounds__(256) void k_scan1(const int* __restrict__ deg,
    int* __restrict__ pos, int* __restrict__ bsum, int M){
  __shared__ int lds[256];
  int t = threadIdx.x;
  int base = blockIdx.x*2048 + t*8;
  int v[8]; int s = 0;
  #pragma unroll
  for (int j=0;j<8;++j){ int idx=base+j; v[j] = (idx<M)? deg[idx]:0; s += v[j]; }
  lds[t] = s; __syncthreads();
  for (int off=1; off<256; off<<=1){
    int tmp = (t>=off)? lds[t-off]:0;
    __syncthreads();
    lds[t] += tmp;
    __syncthreads();
  }
  int incl = lds[t];
  int excl = incl - s;
  if (t==255) bsum[blockIdx.x] = incl;
  int run = excl;
  #pragma unroll
  for (int j=0;j<8;++j){ int idx=base+j; if (idx<M) pos[idx]=run; run+=v[j]; }
}

__global__ __launch_bounds__(256) void k_scan2(int* __restrict__ bsum, int NB){
  __shared__ int lds[256];
  int t = threadIdx.x;
  int val = (t<NB)? bsum[t]:0;
  lds[t]=val; __syncthreads();
  for (int off=1; off<256; off<<=1){
    int tmp=(t>=off)? lds[t-off]:0;
    __syncthreads();
    lds[t]+=tmp;
    __syncthreads();
  }
  if (t<NB) bsum[t] = lds[t]-val;   // exclusive
}

__global__ __launch_bounds__(256) void k_scan3(int* __restrict__ pos,
    const int* __restrict__ bsum, int M){
  int t = threadIdx.x;
  int base = blockIdx.x*2048 + t*8;
  int add = bsum[blockIdx.x];
  #pragma unroll
  for (int j=0;j<8;++j){ int idx=base+j; if (idx<M) pos[idx]+=add; }
}

// pos[] mutates to segment END (start = pos-deg)
__global__ __launch_bounds__(256) void k_scatter(const int* __restrict__ ei,
    const int* __restrict__ et, int* __restrict__ pos, int* __restrict__ ssrc, int E){
  int e = blockIdx.x*256 + threadIdx.x;
  if (e<E){
    int src = ei[e], dst = ei[E+e], ty = et[e];
    int p = atomicAdd(&pos[dst*2+ty], 1);
    ssrc[p] = src;
  }
}

// ----------------------- gather (64-ch bf16 features) ---------------------
// LDS-free, full occupancy. One wave = 2 nodes; both relation segments are
// contiguous in CSR (one merged edge stream + per-edge relation select).
// 16 lanes cooperate on one 128B row; 4 edges per node per load round.
__global__ __launch_bounds__(256) void k_gather64(
    const ushort* __restrict__ hp, const int* __restrict__ deg,
    const int* __restrict__ pos, const int* __restrict__ ssrc,
    ushort* __restrict__ sn, int N)
{
  int lane = threadIdx.x & 63;
  int wid  = (blockIdx.x*256 + threadIdx.x) >> 6;
  int c4 = lane & 15, eg = lane >> 4;
  int nA = wid*2, nB = nA+1;
  if (nA >= N) return;
  int d0A = deg[2*nA], d1A = deg[2*nA+1];
  int pA  = pos[2*nA] - d0A;
  int cA  = d0A + d1A;
  int d0B = 0, d1B = 0, pB = 0, cB = 0;
  if (nB < N){ d0B = deg[2*nB]; d1B = deg[2*nB+1]; pB = pos[2*nB]-d0B; cB = d0B+d1B; }

  float4 s0A={0,0,0,0}, s1A={0,0,0,0}, s0B={0,0,0,0}, s1B={0,0,0,0};
  int jA = 0, jB = 0;
  while (jA < cA || jB < cB){
    int tA = cA - jA; if (tA > 64) tA = 64;
    int tB = cB - jB; if (tB > 64) tB = 64;
    int svA = (lane < tA) ? ssrc[pA + jA + lane] : 0;
    int svB = (lane < tB) ? ssrc[pB + jB + lane] : 0;
    int mt = tA > tB ? tA : tB;
    for (int e = 0; e < mt; e += 4){
      int idx = e + eg;
      int siA = __shfl(svA, idx), siB = __shfl(svB, idx);
      uint2 wA = {0u,0u}, wB = {0u,0u};
      if (idx < tA) wA = *(const uint2*)(hp + (size_t)siA*64 + c4*4);
      if (idx < tB) wB = *(const uint2*)(hp + (size_t)siB*64 + c4*4);
      float4 fA = bf4cvt(wA), fB = bf4cvt(wB);
      accsel(s0A, s1A, fA, (jA + idx) < d0A);
      accsel(s0B, s1B, fB, (jB + idx) < d0B);
    }
    jA += tA; jB += tB;
  }
  redf4(s0A); redf4(s1A); redf4(s0B); redf4(s1B);
  float i0A = 1.f/(float)(d0A>1?d0A:1), i1A = 1.f/(float)(d1A>1?d1A:1);
  float i0B = 1.f/(float)(d0B>1?d0B:1), i1B = 1.f/(float)(d1B>1?d1B:1);
  s0A.x*=i0A; s0A.y*=i0A; s0A.z*=i0A; s0A.w*=i0A;
  s1A.x*=i1A; s1A.y*=i1A; s1A.z*=i1A; s1A.w*=i1A;
  s0B.x*=i0B; s0B.y*=i0B; s0B.z*=i0B; s0B.w*=i0B;
  s1B.x*=i1B; s1B.y*=i1B; s1B.z*=i1B; s1B.w*=i1B;
  // lanes 0-15: (A,rel0) 16-31: (A,rel1) 32-47: (B,rel0) 48-63: (B,rel1)
  float4 v = (lane < 32) ? ((lane < 16) ? s0A : s1A)
                         : ((lane < 48) ? s0B : s1B);
  int n   = (lane < 32) ? nA : nB;
  int rel = (lane >> 4) & 1;
  if (n < N){
    uint2 pkt; pkt.x = bfpack2(v.x, v.y); pkt.y = bfpack2(v.z, v.w);
    *(uint2*)(sn + (size_t)n*128 + rel*64 + c4*4) = pkt;
  }
}

// ------------------------ gather (8-ch f32 input x) -----------------------
// 8 lanes per 32B row; 8 edges per node per load round; dual node.
__global__ __launch_bounds__(256) void k_gather8(
    const float* __restrict__ xp, const int* __restrict__ deg,
    const int* __restrict__ pos, const int* __restrict__ ssrc,
    float* __restrict__ sn1, int N)
{
  int lane = threadIdx.x & 63;
  int wid  = (blockIdx.x*256 + threadIdx.x) >> 6;
  int c = lane & 7, eg = lane >> 3;
  int nA = wid*2, nB = nA+1;
  if (nA >= N) return;
  int d0A = deg[2*nA], d1A = deg[2*nA+1];
  int pA  = pos[2*nA] - d0A;
  int cA  = d0A + d1A;
  int d0B = 0, d1B = 0, pB = 0, cB = 0;
  if (nB < N){ d0B = deg[2*nB]; d1B = deg[2*nB+1]; pB = pos[2*nB]-d0B; cB = d0B+d1B; }

  float s0A=0.f, s1A=0.f, s0B=0.f, s1B=0.f;
  int jA = 0, jB = 0;
  while (jA < cA || jB < cB){
    int tA = cA - jA; if (tA > 64) tA = 64;
    int tB = cB - jB; if (tB > 64) tB = 64;
    int svA = (lane < tA) ? ssrc[pA + jA + lane] : 0;
    int svB = (lane < tB) ? ssrc[pB + jB + lane] : 0;
    int mt = tA > tB ? tA : tB;
    for (int e = 0; e < mt; e += 8){
      int idx = e + eg;
      int siA = __shfl(svA, idx), siB = __shfl(svB, idx);
      float vA = 0.f, vB = 0.f;
      if (idx < tA) vA = xp[(size_t)siA*8 + c];
      if (idx < tB) vB = xp[(size_t)siB*8 + c];
      bool r0A = (jA + idx) < d0A, r0B = (jB + idx) < d0B;
      s0A += r0A ? vA : 0.f;  s1A += r0A ? 0.f : vA;
      s0B += r0B ? vB : 0.f;  s1B += r0B ? 0.f : vB;
    }
    jA += tA; jB += tB;
  }
  #pragma unroll
  for (int off=8; off<64; off<<=1){
    s0A += __shfl_xor(s0A, off); s1A += __shfl_xor(s1A, off);
    s0B += __shfl_xor(s0B, off); s1B += __shfl_xor(s1B, off);
  }
  s0A *= 1.f/(float)(d0A>1?d0A:1);  s1A *= 1.f/(float)(d1A>1?d1A:1);
  s0B *= 1.f/(float)(d0B>1?d0B:1);  s1B *= 1.f/(float)(d1B>1?d1B:1);
  // lanes 0-7:(A,r0) 8-15:(A,r1) 16-23:(B,r0) 24-31:(B,r1)
  if (lane < 32){
    float v = (lane < 16) ? ((lane & 8) ? s1A : s0A)
                          : ((lane & 8) ? s1B : s0B);
    int n = (lane < 16) ? nA : nB;
    if (n < N) sn1[(size_t)n*16 + (lane & 15)] = v;
  }
}

// ----------------------- GEMM layers 2/3 (K=192) --------------------------
#define AST 196
template<int RELU, int OUTBF>
__global__ __launch_bounds__(256) void k_mm192(
    const ushort* __restrict__ sn,   // [N,128] bf16 (rel0|rel1 means)
    const ushort* __restrict__ hp,   // [N,64]  bf16 self
    const float* __restrict__ Wl,    // [128,64]
    const float* __restrict__ rootp, // [64,64]
    const float* __restrict__ bias, void* __restrict__ hout_, int N)
{
  __shared__ float A[64*AST];
  int t = threadIdx.x;
  int nb = blockIdx.x*64;
  // phase 1: coalesced copy Sn -> A[:,0:128], h -> A[:,128:192]
  #pragma unroll
  for (int k=0;k<4;++k){
    int q = k*256 + t;
    int nl = q>>4, off = q&15;
    int n = nb + nl;
    uint4 w = {0,0,0,0};
    if (n < N) w = *(const uint4*)(sn + (size_t)n*128 + off*8);
    float2 a = bf2cvt(w.x), b = bf2cvt(w.y), c = bf2cvt(w.z), d = bf2cvt(w.w);
    float* dst = &A[nl*AST + off*8];
    float4 lo = {a.x,a.y,b.x,b.y}, hi = {c.x,c.y,d.x,d.y};
    *(float4*)dst = lo; *(float4*)(dst+4) = hi;
  }
  #pragma unroll
  for (int k=0;k<2;++k){
    int q = k*256 + t;
    int nl = q>>3, off = q&7;
    int n = nb + nl;
    uint4 w = {0,0,0,0};
    if (n < N) w = *(const uint4*)(hp + (size_t)n*64 + off*8);
    float2 a = bf2cvt(w.x), b = bf2cvt(w.y), c = bf2cvt(w.z), d = bf2cvt(w.w);
    float* dst = &A[nl*AST + 128 + off*8];
    float4 lo = {a.x,a.y,b.x,b.y}, hi = {c.x,c.y,d.x,d.y};
    *(float4*)dst = lo; *(float4*)(dst+4) = hi;
  }
  __syncthreads();
  // phase 2: 4 nodes x 4 outs per thread (proven conflict-free)
  int o0 = (t&15)*4, r0 = (t>>4)*4;
  float4 b4 = *(const float4*)(bias+o0);
  float4 a0=b4,a1=b4,a2=b4,a3=b4;
  const float* Ab = &A[r0*AST];
  #pragma unroll 4
  for (int i=0;i<128;++i){
    float4 w = *(const float4*)(Wl + i*64 + o0);
    fma4(a0, Ab[i],       w); fma4(a1, Ab[AST+i],   w);
    fma4(a2, Ab[2*AST+i], w); fma4(a3, Ab[3*AST+i], w);
  }
  #pragma unroll 4
  for (int i=0;i<64;++i){
    float4 w = *(const float4*)(rootp + i*64 + o0);
    fma4(a0, Ab[128+i],       w); fma4(a1, Ab[AST+128+i],   w);
    fma4(a2, Ab[2*AST+128+i], w); fma4(a3, Ab[3*AST+128+i], w);
  }
  float4 accs[4] = {a0,a1,a2,a3};
  #pragma unroll
  for (int q=0;q<4;++q){
    int n = nb + r0 + q;
    if (n < N){
      float4 r = accs[q];
      if (RELU){ r.x=fmaxf(r.x,0.f); r.y=fmaxf(r.y,0.f); r.z=fmaxf(r.z,0.f); r.w=fmaxf(r.w,0.f); }
      if (OUTBF){
        uint2 p; p.x = bfpack2(r.x,r.y); p.y = bfpack2(r.z,r.w);
        *(uint2*)((ushort*)hout_ + (size_t)n*64 + o0) = p;
      } else {
        *(float4*)((float*)hout_ + (size_t)n*64 + o0) = r;
      }
    }
  }
}

// -------------------------- GEMM layer 1 (K=24) ---------------------------
__global__ __launch_bounds__(256) void k_mm24(
    const float* __restrict__ sn1,   // [N,16] f32 (rel0|rel1 means)
    const float* __restrict__ xp,    // [N,8] f32 self
    const float* __restrict__ Wl,    // [16,64]
    const float* __restrict__ rootp, // [8,64]
    const float* __restrict__ bias, ushort* __restrict__ hout, int N)
{
  __shared__ float A[64*25];
  int t = threadIdx.x;
  int nb = blockIdx.x*64;
  #pragma unroll
  for (int k=0;k<4;++k){
    int q = k*256 + t;
    int nl = q>>4, c = q&15;
    int n = nb + nl;
    A[nl*25 + c] = (n < N) ? sn1[(size_t)n*16 + c] : 0.f;
  }
  #pragma unroll
  for (int k=0;k<2;++k){
    int q = k*256 + t;
    int nl = q>>3, c = q&7;
    int n = nb + nl;
    A[nl*25 + 16 + c] = (n < N) ? xp[(size_t)n*8 + c] : 0.f;
  }
  __syncthreads();
  int o0=(t&15)*4, r0=(t>>4)*4;
  float4 b4 = *(const float4*)(bias+o0);
  float4 a0=b4,a1=b4,a2=b4,a3=b4;
  const float* Ab=&A[r0*25];
  #pragma unroll
  for (int i=0;i<16;++i){
    float4 w=*(const float4*)(Wl+i*64+o0);
    fma4(a0,Ab[i],w); fma4(a1,Ab[25+i],w); fma4(a2,Ab[50+i],w); fma4(a3,Ab[75+i],w);
  }
  #pragma unroll
  for (int i=0;i<8;++i){
    float4 w=*(const float4*)(rootp+i*64+o0);
    fma4(a0,Ab[16+i],w); fma4(a1,Ab[41+i],w); fma4(a2,Ab[66+i],w); fma4(a3,Ab[91+i],w);
  }
  float4 accs[4]={a0,a1,a2,a3};
  #pragma unroll
  for (int q=0;q<4;++q){
    int n = nb + r0 + q;
    if (n < N){
      float4 r = accs[q];
      r.x=fmaxf(r.x,0.f); r.y=fmaxf(r.y,0.f); r.z=fmaxf(r.z,0.f); r.w=fmaxf(r.w,0.f);
      uint2 p; p.x = bfpack2(r.x,r.y); p.y = bfpack2(r.z,r.w);
      *(uint2*)(hout + (size_t)n*64 + o0) = p;
    }
  }
}

// ------------------------------- pool + MLP -------------------------------

__device__ __forceinline__ int lowerb(const int* __restrict__ b, int n, int key){
  int lo=0, hi=n;
  while (lo<hi){ int mid=(lo+hi)>>1; if (b[mid]<key) lo=mid+1; else hi=mid; }
  return lo;
}

__global__ __launch_bounds__(256) void k_pool(const float* __restrict__ h,
    const int* __restrict__ batch, float* __restrict__ gp, int N){
  __shared__ float red[256];
  int g=blockIdx.x, t=threadIdx.x;
  int start=lowerb(batch,N,g), end=lowerb(batch,N,g+1);
  int c=t&63, p=t>>6;
  float s=0.f;
  for (int n=start+p; n<end; n+=4) s += h[(size_t)n*64+c];
  red[t]=s; __syncthreads();
  if (t<64) gp[g*64+c] = red[c]+red[64+c]+red[128+c]+red[192+c];
}

__global__ __launch_bounds__(256) void k_clf(const float* __restrict__ gp,
    const float* __restrict__ cW1, const float* __restrict__ cb1,
    const float* __restrict__ cW2, const float* __restrict__ cb2,
    float* __restrict__ out, int G){
  int t=threadIdx.x;
  if (t<G){
    float gv[64];
    #pragma unroll
    for (int i=0;i<64;++i) gv[i]=gp[t*64+i];
    float o=cb2[0];
    for (int j=0;j<32;++j){
      float h=cb1[j];
      #pragma unroll 8
      for (int i=0;i<64;++i) h += gv[i]*cW1[i*32+j];
      o += fmaxf(h,0.f)*cW2[j];
    }
    out[t]=o;
  }
}

extern "C" void kernel_launch(void* const* d_in, const int* in_sizes, int n_in,
                              void* d_out, int out_size, void* d_ws, size_t ws_size,
                              hipStream_t stream){
  const float* x     = (const float*)d_in[0];
  const int*   ei    = (const int*)d_in[1];
  const int*   et    = (const int*)d_in[2];
  const int*   batch = (const int*)d_in[3];
  const float* W1    = (const float*)d_in[4];
  const float* root1 = (const float*)d_in[5];
  const float* b1    = (const float*)d_in[6];
  const float* W2    = (const float*)d_in[7];
  const float* root2 = (const float*)d_in[8];
  const float* b2    = (const float*)d_in[9];
  const float* W3    = (const float*)d_in[10];
  const float* root3 = (const float*)d_in[11];
  const float* b3    = (const float*)d_in[12];
  const float* cW1   = (const float*)d_in[13];
  const float* cb1   = (const float*)d_in[14];
  const float* cW2   = (const float*)d_in[15];
  const float* cb2   = (const float*)d_in[16];
  float* out = (float*)d_out;
  (void)n_in; (void)ws_size;

  int N = in_sizes[0]/8;      // 100000
  int E = in_sizes[2];        // 3200000
  int G = out_size;           // 256
  int M = 2*N;

  char* w = (char*)d_ws;
  auto alloc=[&](size_t bytes)->char*{ char* p=w; w += (bytes+255)&~(size_t)255; return p; };
  int*    deg  = (int*)alloc((size_t)M*4);
  int*    pos  = (int*)alloc((size_t)M*4);
  int*    bsum = (int*)alloc(256*4);
  ushort* snU  = (ushort*)alloc((size_t)N*128*2); // union: sn1 (layer1) / sn (layers 2,3)
  int*    ssrc = (int*)alloc((size_t)E*4);
  ushort* h1   = (ushort*)alloc((size_t)N*64*2);
  ushort* h2   = (ushort*)alloc((size_t)N*64*2);
  float*  gp   = (float*)alloc((size_t)G*64*4);
  float*  sn1  = (float*)snU;                     // [N,16] f32, dead after k_mm24
  float*  hf   = (float*)ssrc;                    // [N,64] f32 aliases ssrc+h1 (both dead at layer-3 GEMM)

  hipMemsetAsync(deg, 0, (size_t)M*4, stream);
  int eb=(E+255)/256;
  k_hist<<<eb,256,0,stream>>>(ei,et,deg,E);
  int NB=(M+2047)/2048;
  k_scan1<<<NB,256,0,stream>>>(deg,pos,bsum,M);
  k_scan2<<<1,256,0,stream>>>(bsum,NB);
  k_scan3<<<NB,256,0,stream>>>(pos,bsum,M);
  k_scatter<<<eb,256,0,stream>>>(ei,et,pos,ssrc,E);

  int gb = (((N+1)/2) + 3) / 4;     // waves = ceil(N/2), 4 waves/block
  int nbk = (N+63)/64;
  // layer 1
  k_gather8 <<<gb,256,0,stream>>>(x,deg,pos,ssrc,sn1,N);
  k_mm24    <<<nbk,256,0,stream>>>(sn1,x,W1,root1,b1,h1,N);
  // layer 2
  k_gather64<<<gb,256,0,stream>>>(h1,deg,pos,ssrc,snU,N);
  k_mm192<1,1><<<nbk,256,0,stream>>>(snU,h1,W2,root2,b2,h2,N);
  // layer 3
  k_gather64<<<gb,256,0,stream>>>(h2,deg,pos,ssrc,snU,N);
  k_mm192<0,0><<<nbk,256,0,stream>>>(snU,h2,W3,root3,b3,hf,N);
  // pool + head
  k_pool<<<G,256,0,stream>>>(hf,batch,gp,N);
  k_clf<<<1,256,0,stream>>>(gp,cW1,cb1,cW2,cb2,out,G);
}

// Round 4
// 575.351 us; speedup vs baseline: 2.2757x; 1.4623x over previous
//
#include <hip/hip_runtime.h>

// ---------------------------------------------------------------------------
// RGCN restructured: aggregate x[src] FIRST (per relation), then one GEMM
//   A = [Sn_rel0 | Sn_rel1 | x_self],  Wcat = [W0; W1; root]
// R4: CSR build via two-level counting sort (256 coarse buckets of 512
//     nodes). All random writes land in cache-resident windows:
//     k_part writes ~42-edge contiguous runs/bucket/block (full lines),
//     k_csr scatters within a 64KB bucket window (L2-resident).
//     Replaces hist(random atomics) + scatter(203MB write amplification).
// ---------------------------------------------------------------------------

typedef unsigned int uint;
typedef unsigned short ushort;

#define EPB 8192   // edges per block in count/partition kernels

__device__ __forceinline__ void fma4(float4& a, float s, const float4& w){
  a.x += s*w.x; a.y += s*w.y; a.z += s*w.z; a.w += s*w.w;
}
__device__ __forceinline__ uint bf1(float f){          // f32 -> bf16 (RNE)
  uint u = __float_as_uint(f);
  return (u + 0x7fffu + ((u>>16)&1u)) >> 16;
}
__device__ __forceinline__ uint bfpack2(float lo, float hi){
  return bf1(lo) | (bf1(hi)<<16);
}
__device__ __forceinline__ float4 bf4cvt(uint2 w){
  float4 r;
  r.x = __uint_as_float(w.x<<16);
  r.y = __uint_as_float(w.x & 0xffff0000u);
  r.z = __uint_as_float(w.y<<16);
  r.w = __uint_as_float(w.y & 0xffff0000u);
  return r;
}
__device__ __forceinline__ float2 bf2cvt(uint w){
  float2 r; r.x = __uint_as_float(w<<16); r.y = __uint_as_float(w & 0xffff0000u);
  return r;
}
__device__ __forceinline__ void redf4(float4& a){
  a.x += __shfl_xor(a.x,16); a.x += __shfl_xor(a.x,32);
  a.y += __shfl_xor(a.y,16); a.y += __shfl_xor(a.y,32);
  a.z += __shfl_xor(a.z,16); a.z += __shfl_xor(a.z,32);
  a.w += __shfl_xor(a.w,16); a.w += __shfl_xor(a.w,32);
}
__device__ __forceinline__ void accsel(float4& s0, float4& s1, float4 f, bool is0){
  s0.x += is0 ? f.x : 0.f;  s1.x += is0 ? 0.f : f.x;
  s0.y += is0 ? f.y : 0.f;  s1.y += is0 ? 0.f : f.y;
  s0.z += is0 ? f.z : 0.f;  s1.z += is0 ? 0.f : f.z;
  s0.w += is0 ? f.w : 0.f;  s1.w += is0 ? 0.f : f.w;
}

// --------------------- CSR build: two-level counting sort ------------------

// coarse bucket histogram (bucket = dst>>9)
__global__ __launch_bounds__(256) void k_count(const int* __restrict__ ei,
    int* __restrict__ bhist, int E){
  __shared__ int h[256];
  int t = threadIdx.x;
  h[t] = 0; __syncthreads();
  int base = blockIdx.x*EPB;
  for (int i=t; i<EPB; i+=256){
    int e = base+i;
    if (e < E) atomicAdd(&h[ei[E+e]>>9], 1);
  }
  __syncthreads();
  if (h[t]) atomicAdd(&bhist[t], h[t]);
}

// exclusive scan of 256 bucket counts; bbase[256]=E; bcur init = bbase
__global__ __launch_bounds__(256) void k_bscan(const int* __restrict__ bhist,
    int* __restrict__ bbase, int* __restrict__ bcur){
  __shared__ int lds[256];
  int t = threadIdx.x;
  int v = bhist[t];
  lds[t] = v; __syncthreads();
  for (int off=1; off<256; off<<=1){
    int tmp = (t>=off)? lds[t-off]:0;
    __syncthreads();
    lds[t] += tmp;
    __syncthreads();
  }
  int excl = lds[t]-v;
  bbase[t] = excl; bcur[t] = excl;
  if (t==255) bbase[256] = excl+v;
}

// partition edges into bucket regions as packed (src<<10)|((dst&511)<<1|ty)
__global__ __launch_bounds__(256) void k_part(const int* __restrict__ ei,
    const int* __restrict__ et, int* __restrict__ bcur,
    uint* __restrict__ bk, int E){
  __shared__ int h[256];
  __shared__ int cur[256];
  int t = threadIdx.x;
  h[t] = 0; __syncthreads();
  int base = blockIdx.x*EPB;
  for (int i=t; i<EPB; i+=256){
    int e = base+i;
    if (e < E) atomicAdd(&h[ei[E+e]>>9], 1);
  }
  __syncthreads();
  int c = h[t];
  cur[t] = c ? atomicAdd(&bcur[t], c) : 0;
  __syncthreads();
  for (int i=t; i<EPB; i+=256){
    int e = base+i;
    if (e < E){
      int s = ei[e], d = ei[E+e], ty = et[e];
      int p = atomicAdd(&cur[d>>9], 1);
      bk[p] = ((uint)s<<10) | (uint)(((d&511)<<1) | ty);
    }
  }
}

// per-bucket fine sort: 1024 segments (512 nodes x 2 rels). Writes deg, pos
// (segment START), and ssrc (scatter confined to 64KB bucket window).
__global__ __launch_bounds__(256) void k_csr(const uint* __restrict__ bk,
    const int* __restrict__ bbase, int* __restrict__ deg,
    int* __restrict__ pos, int* __restrict__ ssrc, int N){
  __shared__ int h[1024];
  __shared__ int cur[1024];
  __shared__ int ws[256];
  int b = blockIdx.x, t = threadIdx.x;
  int start = bbase[b], end = bbase[b+1];
  h[t]=0; h[256+t]=0; h[512+t]=0; h[768+t]=0;
  __syncthreads();
  for (int i=start+t; i<end; i+=256) atomicAdd(&h[bk[i]&1023], 1);
  __syncthreads();
  int c0=h[4*t], c1=h[4*t+1], c2=h[4*t+2], c3=h[4*t+3];
  int s = c0+c1+c2+c3;
  ws[t] = s; __syncthreads();
  for (int off=1; off<256; off<<=1){
    int tmp = (t>=off)? ws[t-off]:0;
    __syncthreads();
    ws[t] += tmp;
    __syncthreads();
  }
  int base0 = start + ws[t] - s;
  cur[4*t]   = base0;
  cur[4*t+1] = base0 + c0;
  cur[4*t+2] = base0 + c0 + c1;
  cur[4*t+3] = base0 + c0 + c1 + c2;
  int gk = b*1024 + 4*t;
  int nodeA = (b<<9) + 2*t, nodeB = nodeA + 1;
  if (nodeA < N){
    deg[gk]   = c0; deg[gk+1] = c1;
    pos[gk]   = base0; pos[gk+1] = base0 + c0;
  }
  if (nodeB < N){
    deg[gk+2] = c2; deg[gk+3] = c3;
    pos[gk+2] = base0 + c0 + c1; pos[gk+3] = base0 + c0 + c1 + c2;
  }
  __syncthreads();
  for (int i=start+t; i<end; i+=256){
    uint w = bk[i];
    int p = atomicAdd(&cur[w & 1023], 1);
    ssrc[p] = (int)(w >> 10);
  }
}

// ----------------------- gather (64-ch bf16 features) ---------------------
// LDS-free, full occupancy. One wave = 2 nodes; both relation segments are
// contiguous in CSR (merged edge stream + per-edge relation select).
__global__ __launch_bounds__(256) void k_gather64(
    const ushort* __restrict__ hp, const int* __restrict__ deg,
    const int* __restrict__ pos, const int* __restrict__ ssrc,
    ushort* __restrict__ sn, int N)
{
  int lane = threadIdx.x & 63;
  int wid  = (blockIdx.x*256 + threadIdx.x) >> 6;
  int c4 = lane & 15, eg = lane >> 4;
  int nA = wid*2, nB = nA+1;
  if (nA >= N) return;
  int d0A = deg[2*nA], d1A = deg[2*nA+1];
  int pA  = pos[2*nA];
  int cA  = d0A + d1A;
  int d0B = 0, d1B = 0, pB = 0, cB = 0;
  if (nB < N){ d0B = deg[2*nB]; d1B = deg[2*nB+1]; pB = pos[2*nB]; cB = d0B+d1B; }

  float4 s0A={0,0,0,0}, s1A={0,0,0,0}, s0B={0,0,0,0}, s1B={0,0,0,0};
  int jA = 0, jB = 0;
  while (jA < cA || jB < cB){
    int tA = cA - jA; if (tA > 64) tA = 64;
    int tB = cB - jB; if (tB > 64) tB = 64;
    int svA = (lane < tA) ? ssrc[pA + jA + lane] : 0;
    int svB = (lane < tB) ? ssrc[pB + jB + lane] : 0;
    int mt = tA > tB ? tA : tB;
    for (int e = 0; e < mt; e += 4){
      int idx = e + eg;
      int siA = __shfl(svA, idx), siB = __shfl(svB, idx);
      uint2 wA = {0u,0u}, wB = {0u,0u};
      if (idx < tA) wA = *(const uint2*)(hp + (size_t)siA*64 + c4*4);
      if (idx < tB) wB = *(const uint2*)(hp + (size_t)siB*64 + c4*4);
      float4 fA = bf4cvt(wA), fB = bf4cvt(wB);
      accsel(s0A, s1A, fA, (jA + idx) < d0A);
      accsel(s0B, s1B, fB, (jB + idx) < d0B);
    }
    jA += tA; jB += tB;
  }
  redf4(s0A); redf4(s1A); redf4(s0B); redf4(s1B);
  float i0A = 1.f/(float)(d0A>1?d0A:1), i1A = 1.f/(float)(d1A>1?d1A:1);
  float i0B = 1.f/(float)(d0B>1?d0B:1), i1B = 1.f/(float)(d1B>1?d1B:1);
  s0A.x*=i0A; s0A.y*=i0A; s0A.z*=i0A; s0A.w*=i0A;
  s1A.x*=i1A; s1A.y*=i1A; s1A.z*=i1A; s1A.w*=i1A;
  s0B.x*=i0B; s0B.y*=i0B; s0B.z*=i0B; s0B.w*=i0B;
  s1B.x*=i1B; s1B.y*=i1B; s1B.z*=i1B; s1B.w*=i1B;
  // lanes 0-15: (A,rel0) 16-31: (A,rel1) 32-47: (B,rel0) 48-63: (B,rel1)
  float4 v = (lane < 32) ? ((lane < 16) ? s0A : s1A)
                         : ((lane < 48) ? s0B : s1B);
  int n   = (lane < 32) ? nA : nB;
  int rel = (lane >> 4) & 1;
  if (n < N){
    uint2 pkt; pkt.x = bfpack2(v.x, v.y); pkt.y = bfpack2(v.z, v.w);
    *(uint2*)(sn + (size_t)n*128 + rel*64 + c4*4) = pkt;
  }
}

// ------------------------ gather (8-ch f32 input x) -----------------------
__global__ __launch_bounds__(256) void k_gather8(
    const float* __restrict__ xp, const int* __restrict__ deg,
    const int* __restrict__ pos, const int* __restrict__ ssrc,
    float* __restrict__ sn1, int N)
{
  int lane = threadIdx.x & 63;
  int wid  = (blockIdx.x*256 + threadIdx.x) >> 6;
  int c = lane & 7, eg = lane >> 3;
  int nA = wid*2, nB = nA+1;
  if (nA >= N) return;
  int d0A = deg[2*nA], d1A = deg[2*nA+1];
  int pA  = pos[2*nA];
  int cA  = d0A + d1A;
  int d0B = 0, d1B = 0, pB = 0, cB = 0;
  if (nB < N){ d0B = deg[2*nB]; d1B = deg[2*nB+1]; pB = pos[2*nB]; cB = d0B+d1B; }

  float s0A=0.f, s1A=0.f, s0B=0.f, s1B=0.f;
  int jA = 0, jB = 0;
  while (jA < cA || jB < cB){
    int tA = cA - jA; if (tA > 64) tA = 64;
    int tB = cB - jB; if (tB > 64) tB = 64;
    int svA = (lane < tA) ? ssrc[pA + jA + lane] : 0;
    int svB = (lane < tB) ? ssrc[pB + jB + lane] : 0;
    int mt = tA > tB ? tA : tB;
    for (int e = 0; e < mt; e += 8){
      int idx = e + eg;
      int siA = __shfl(svA, idx), siB = __shfl(svB, idx);
      float vA = 0.f, vB = 0.f;
      if (idx < tA) vA = xp[(size_t)siA*8 + c];
      if (idx < tB) vB = xp[(size_t)siB*8 + c];
      bool r0A = (jA + idx) < d0A, r0B = (jB + idx) < d0B;
      s0A += r0A ? vA : 0.f;  s1A += r0A ? 0.f : vA;
      s0B += r0B ? vB : 0.f;  s1B += r0B ? 0.f : vB;
    }
    jA += tA; jB += tB;
  }
  #pragma unroll
  for (int off=8; off<64; off<<=1){
    s0A += __shfl_xor(s0A, off); s1A += __shfl_xor(s1A, off);
    s0B += __shfl_xor(s0B, off); s1B += __shfl_xor(s1B, off);
  }
  s0A *= 1.f/(float)(d0A>1?d0A:1);  s1A *= 1.f/(float)(d1A>1?d1A:1);
  s0B *= 1.f/(float)(d0B>1?d0B:1);  s1B *= 1.f/(float)(d1B>1?d1B:1);
  if (lane < 32){
    float v = (lane < 16) ? ((lane & 8) ? s1A : s0A)
                          : ((lane & 8) ? s1B : s0B);
    int n = (lane < 16) ? nA : nB;
    if (n < N) sn1[(size_t)n*16 + (lane & 15)] = v;
  }
}

// ----------------------- GEMM layers 2/3 (K=192) --------------------------
#define AST 196
template<int RELU, int OUTBF>
__global__ __launch_bounds__(256) void k_mm192(
    const ushort* __restrict__ sn,   // [N,128] bf16 (rel0|rel1 means)
    const ushort* __restrict__ hp,   // [N,64]  bf16 self
    const float* __restrict__ Wl,    // [128,64]
    const float* __restrict__ rootp, // [64,64]
    const float* __restrict__ bias, void* __restrict__ hout_, int N)
{
  __shared__ float A[64*AST];
  int t = threadIdx.x;
  int nb = blockIdx.x*64;
  #pragma unroll
  for (int k=0;k<4;++k){
    int q = k*256 + t;
    int nl = q>>4, off = q&15;
    int n = nb + nl;
    uint4 w = {0,0,0,0};
    if (n < N) w = *(const uint4*)(sn + (size_t)n*128 + off*8);
    float2 a = bf2cvt(w.x), b = bf2cvt(w.y), c = bf2cvt(w.z), d = bf2cvt(w.w);
    float* dst = &A[nl*AST + off*8];
    float4 lo = {a.x,a.y,b.x,b.y}, hi = {c.x,c.y,d.x,d.y};
    *(float4*)dst = lo; *(float4*)(dst+4) = hi;
  }
  #pragma unroll
  for (int k=0;k<2;++k){
    int q = k*256 + t;
    int nl = q>>3, off = q&7;
    int n = nb + nl;
    uint4 w = {0,0,0,0};
    if (n < N) w = *(const uint4*)(hp + (size_t)n*64 + off*8);
    float2 a = bf2cvt(w.x), b = bf2cvt(w.y), c = bf2cvt(w.z), d = bf2cvt(w.w);
    float* dst = &A[nl*AST + 128 + off*8];
    float4 lo = {a.x,a.y,b.x,b.y}, hi = {c.x,c.y,d.x,d.y};
    *(float4*)dst = lo; *(float4*)(dst+4) = hi;
  }
  __syncthreads();
  int o0 = (t&15)*4, r0 = (t>>4)*4;
  float4 b4 = *(const float4*)(bias+o0);
  float4 a0=b4,a1=b4,a2=b4,a3=b4;
  const float* Ab = &A[r0*AST];
  #pragma unroll 4
  for (int i=0;i<128;++i){
    float4 w = *(const float4*)(Wl + i*64 + o0);
    fma4(a0, Ab[i],       w); fma4(a1, Ab[AST+i],   w);
    fma4(a2, Ab[2*AST+i], w); fma4(a3, Ab[3*AST+i], w);
  }
  #pragma unroll 4
  for (int i=0;i<64;++i){
    float4 w = *(const float4*)(rootp + i*64 + o0);
    fma4(a0, Ab[128+i],       w); fma4(a1, Ab[AST+128+i],   w);
    fma4(a2, Ab[2*AST+128+i], w); fma4(a3, Ab[3*AST+128+i], w);
  }
  float4 accs[4] = {a0,a1,a2,a3};
  #pragma unroll
  for (int q=0;q<4;++q){
    int n = nb + r0 + q;
    if (n < N){
      float4 r = accs[q];
      if (RELU){ r.x=fmaxf(r.x,0.f); r.y=fmaxf(r.y,0.f); r.z=fmaxf(r.z,0.f); r.w=fmaxf(r.w,0.f); }
      if (OUTBF){
        uint2 p; p.x = bfpack2(r.x,r.y); p.y = bfpack2(r.z,r.w);
        *(uint2*)((ushort*)hout_ + (size_t)n*64 + o0) = p;
      } else {
        *(float4*)((float*)hout_ + (size_t)n*64 + o0) = r;
      }
    }
  }
}

// -------------------------- GEMM layer 1 (K=24) ---------------------------
__global__ __launch_bounds__(256) void k_mm24(
    const float* __restrict__ sn1,   // [N,16] f32
    const float* __restrict__ xp,    // [N,8] f32 self
    const float* __restrict__ Wl,    // [16,64]
    const float* __restrict__ rootp, // [8,64]
    const float* __restrict__ bias, ushort* __restrict__ hout, int N)
{
  __shared__ float A[64*25];
  int t = threadIdx.x;
  int nb = blockIdx.x*64;
  #pragma unroll
  for (int k=0;k<4;++k){
    int q = k*256 + t;
    int nl = q>>4, c = q&15;
    int n = nb + nl;
    A[nl*25 + c] = (n < N) ? sn1[(size_t)n*16 + c] : 0.f;
  }
  #pragma unroll
  for (int k=0;k<2;++k){
    int q = k*256 + t;
    int nl = q>>3, c = q&7;
    int n = nb + nl;
    A[nl*25 + 16 + c] = (n < N) ? xp[(size_t)n*8 + c] : 0.f;
  }
  __syncthreads();
  int o0=(t&15)*4, r0=(t>>4)*4;
  float4 b4 = *(const float4*)(bias+o0);
  float4 a0=b4,a1=b4,a2=b4,a3=b4;
  const float* Ab=&A[r0*25];
  #pragma unroll
  for (int i=0;i<16;++i){
    float4 w=*(const float4*)(Wl+i*64+o0);
    fma4(a0,Ab[i],w); fma4(a1,Ab[25+i],w); fma4(a2,Ab[50+i],w); fma4(a3,Ab[75+i],w);
  }
  #pragma unroll
  for (int i=0;i<8;++i){
    float4 w=*(const float4*)(rootp+i*64+o0);
    fma4(a0,Ab[16+i],w); fma4(a1,Ab[41+i],w); fma4(a2,Ab[66+i],w); fma4(a3,Ab[91+i],w);
  }
  float4 accs[4]={a0,a1,a2,a3};
  #pragma unroll
  for (int q=0;q<4;++q){
    int n = nb + r0 + q;
    if (n < N){
      float4 r = accs[q];
      r.x=fmaxf(r.x,0.f); r.y=fmaxf(r.y,0.f); r.z=fmaxf(r.z,0.f); r.w=fmaxf(r.w,0.f);
      uint2 p; p.x = bfpack2(r.x,r.y); p.y = bfpack2(r.z,r.w);
      *(uint2*)(hout + (size_t)n*64 + o0) = p;
    }
  }
}

// ------------------------------- pool + MLP -------------------------------

__device__ __forceinline__ int lowerb(const int* __restrict__ b, int n, int key){
  int lo=0, hi=n;
  while (lo<hi){ int mid=(lo+hi)>>1; if (b[mid]<key) lo=mid+1; else hi=mid; }
  return lo;
}

__global__ __launch_bounds__(256) void k_pool(const float* __restrict__ h,
    const int* __restrict__ batch, float* __restrict__ gp, int N){
  __shared__ float red[256];
  int g=blockIdx.x, t=threadIdx.x;
  int start=lowerb(batch,N,g), end=lowerb(batch,N,g+1);
  int c=t&63, p=t>>6;
  float s=0.f;
  for (int n=start+p; n<end; n+=4) s += h[(size_t)n*64+c];
  red[t]=s; __syncthreads();
  if (t<64) gp[g*64+c] = red[c]+red[64+c]+red[128+c]+red[192+c];
}

__global__ __launch_bounds__(256) void k_clf(const float* __restrict__ gp,
    const float* __restrict__ cW1, const float* __restrict__ cb1,
    const float* __restrict__ cW2, const float* __restrict__ cb2,
    float* __restrict__ out, int G){
  int t=threadIdx.x;
  if (t<G){
    float gv[64];
    #pragma unroll
    for (int i=0;i<64;++i) gv[i]=gp[t*64+i];
    float o=cb2[0];
    for (int j=0;j<32;++j){
      float h=cb1[j];
      #pragma unroll 8
      for (int i=0;i<64;++i) h += gv[i]*cW1[i*32+j];
      o += fmaxf(h,0.f)*cW2[j];
    }
    out[t]=o;
  }
}

extern "C" void kernel_launch(void* const* d_in, const int* in_sizes, int n_in,
                              void* d_out, int out_size, void* d_ws, size_t ws_size,
                              hipStream_t stream){
  const float* x     = (const float*)d_in[0];
  const int*   ei    = (const int*)d_in[1];
  const int*   et    = (const int*)d_in[2];
  const int*   batch = (const int*)d_in[3];
  const float* W1    = (const float*)d_in[4];
  const float* root1 = (const float*)d_in[5];
  const float* b1    = (const float*)d_in[6];
  const float* W2    = (const float*)d_in[7];
  const float* root2 = (const float*)d_in[8];
  const float* b2    = (const float*)d_in[9];
  const float* W3    = (const float*)d_in[10];
  const float* root3 = (const float*)d_in[11];
  const float* b3    = (const float*)d_in[12];
  const float* cW1   = (const float*)d_in[13];
  const float* cb1   = (const float*)d_in[14];
  const float* cW2   = (const float*)d_in[15];
  const float* cb2   = (const float*)d_in[16];
  float* out = (float*)d_out;
  (void)n_in; (void)ws_size;

  int N = in_sizes[0]/8;      // 100000
  int E = in_sizes[2];        // 3200000
  int G = out_size;           // 256
  int M = 2*N;

  char* w = (char*)d_ws;
  auto alloc=[&](size_t bytes)->char*{ char* p=w; w += (bytes+255)&~(size_t)255; return p; };
  int*    bhist = (int*)alloc(256*4);
  int*    bbase = (int*)alloc(257*4);
  int*    bcur  = (int*)alloc(256*4);
  int*    ssrc  = (int*)alloc((size_t)E*4);
  int*    deg   = (int*)alloc((size_t)M*4);
  int*    pos   = (int*)alloc((size_t)M*4);
  ushort* h1    = (ushort*)alloc((size_t)N*64*2);
  ushort* snU   = (ushort*)alloc((size_t)N*128*2);
  ushort* h2    = (ushort*)alloc((size_t)N*64*2);  // bk aliases this (E*4 == N*128)
  float*  gp    = (float*)alloc((size_t)G*64*4);
  uint*   bk    = (uint*)h2;                       // dead before h2 is written
  float*  sn1   = (float*)snU;                     // [N,16] f32, dead after k_mm24
  float*  hf    = (float*)ssrc;                    // [N,64] f32 spans ssrc+deg+pos+h1 (27.2MB>=25.6MB), all dead at layer-3 GEMM

  hipMemsetAsync(bhist, 0, 256*4, stream);
  int nbE = (E + EPB - 1)/EPB;
  k_count<<<nbE,256,0,stream>>>(ei,bhist,E);
  k_bscan<<<1,256,0,stream>>>(bhist,bbase,bcur);
  k_part <<<nbE,256,0,stream>>>(ei,et,bcur,bk,E);
  k_csr  <<<256,256,0,stream>>>(bk,bbase,deg,pos,ssrc,N);

  int gb = (((N+1)/2) + 3) / 4;     // waves = ceil(N/2), 4 waves/block
  int nbk = (N+63)/64;
  // layer 1
  k_gather8 <<<gb,256,0,stream>>>(x,deg,pos,ssrc,sn1,N);
  k_mm24    <<<nbk,256,0,stream>>>(sn1,x,W1,root1,b1,h1,N);
  // layer 2
  k_gather64<<<gb,256,0,stream>>>(h1,deg,pos,ssrc,snU,N);
  k_mm192<1,1><<<nbk,256,0,stream>>>(snU,h1,W2,root2,b2,h2,N);
  // layer 3
  k_gather64<<<gb,256,0,stream>>>(h2,deg,pos,ssrc,snU,N);
  k_mm192<0,0><<<nbk,256,0,stream>>>(snU,h2,W3,root3,b3,hf,N);
  // pool + head
  k_pool<<<G,256,0,stream>>>(hf,batch,gp,N);
  k_clf<<<1,256,0,stream>>>(gp,cW1,cb1,cW2,cb2,out,G);
}

// Round 5
// 510.074 us; speedup vs baseline: 2.5669x; 1.1280x over previous
//
#include <hip/hip_runtime.h>

// ---------------------------------------------------------------------------
// RGCN restructured: aggregate x[src] FIRST (per relation), then one GEMM
//   A = [Sn_rel0 | Sn_rel1 | x_self],  Wcat = [W0; W1; root]
// R4: CSR build via two-level counting sort (cache-resident random writes).
// R5: k_clf parallelized — one wave per graph (was: 1 block total, 65us,
//     0.04% occupancy, pure latency chain). ~50 inst/wave, 256 waves.
// ---------------------------------------------------------------------------

typedef unsigned int uint;
typedef unsigned short ushort;

#define EPB 8192   // edges per block in count/partition kernels

__device__ __forceinline__ void fma4(float4& a, float s, const float4& w){
  a.x += s*w.x; a.y += s*w.y; a.z += s*w.z; a.w += s*w.w;
}
__device__ __forceinline__ uint bf1(float f){          // f32 -> bf16 (RNE)
  uint u = __float_as_uint(f);
  return (u + 0x7fffu + ((u>>16)&1u)) >> 16;
}
__device__ __forceinline__ uint bfpack2(float lo, float hi){
  return bf1(lo) | (bf1(hi)<<16);
}
__device__ __forceinline__ float4 bf4cvt(uint2 w){
  float4 r;
  r.x = __uint_as_float(w.x<<16);
  r.y = __uint_as_float(w.x & 0xffff0000u);
  r.z = __uint_as_float(w.y<<16);
  r.w = __uint_as_float(w.y & 0xffff0000u);
  return r;
}
__device__ __forceinline__ float2 bf2cvt(uint w){
  float2 r; r.x = __uint_as_float(w<<16); r.y = __uint_as_float(w & 0xffff0000u);
  return r;
}
__device__ __forceinline__ void redf4(float4& a){
  a.x += __shfl_xor(a.x,16); a.x += __shfl_xor(a.x,32);
  a.y += __shfl_xor(a.y,16); a.y += __shfl_xor(a.y,32);
  a.z += __shfl_xor(a.z,16); a.z += __shfl_xor(a.z,32);
  a.w += __shfl_xor(a.w,16); a.w += __shfl_xor(a.w,32);
}
__device__ __forceinline__ void accsel(float4& s0, float4& s1, float4 f, bool is0){
  s0.x += is0 ? f.x : 0.f;  s1.x += is0 ? 0.f : f.x;
  s0.y += is0 ? f.y : 0.f;  s1.y += is0 ? 0.f : f.y;
  s0.z += is0 ? f.z : 0.f;  s1.z += is0 ? 0.f : f.z;
  s0.w += is0 ? f.w : 0.f;  s1.w += is0 ? 0.f : f.w;
}

// --------------------- CSR build: two-level counting sort ------------------

__global__ __launch_bounds__(256) void k_count(const int* __restrict__ ei,
    int* __restrict__ bhist, int E){
  __shared__ int h[256];
  int t = threadIdx.x;
  h[t] = 0; __syncthreads();
  int base = blockIdx.x*EPB;
  for (int i=t; i<EPB; i+=256){
    int e = base+i;
    if (e < E) atomicAdd(&h[ei[E+e]>>9], 1);
  }
  __syncthreads();
  if (h[t]) atomicAdd(&bhist[t], h[t]);
}

__global__ __launch_bounds__(256) void k_bscan(const int* __restrict__ bhist,
    int* __restrict__ bbase, int* __restrict__ bcur){
  __shared__ int lds[256];
  int t = threadIdx.x;
  int v = bhist[t];
  lds[t] = v; __syncthreads();
  for (int off=1; off<256; off<<=1){
    int tmp = (t>=off)? lds[t-off]:0;
    __syncthreads();
    lds[t] += tmp;
    __syncthreads();
  }
  int excl = lds[t]-v;
  bbase[t] = excl; bcur[t] = excl;
  if (t==255) bbase[256] = excl+v;
}

// partition edges into bucket regions as packed (src<<10)|((dst&511)<<1|ty)
__global__ __launch_bounds__(256) void k_part(const int* __restrict__ ei,
    const int* __restrict__ et, int* __restrict__ bcur,
    uint* __restrict__ bk, int E){
  __shared__ int h[256];
  __shared__ int cur[256];
  int t = threadIdx.x;
  h[t] = 0; __syncthreads();
  int base = blockIdx.x*EPB;
  for (int i=t; i<EPB; i+=256){
    int e = base+i;
    if (e < E) atomicAdd(&h[ei[E+e]>>9], 1);
  }
  __syncthreads();
  int c = h[t];
  cur[t] = c ? atomicAdd(&bcur[t], c) : 0;
  __syncthreads();
  for (int i=t; i<EPB; i+=256){
    int e = base+i;
    if (e < E){
      int s = ei[e], d = ei[E+e], ty = et[e];
      int p = atomicAdd(&cur[d>>9], 1);
      bk[p] = ((uint)s<<10) | (uint)(((d&511)<<1) | ty);
    }
  }
}

// per-bucket fine sort: deg, pos (segment START), ssrc within 64KB window
__global__ __launch_bounds__(256) void k_csr(const uint* __restrict__ bk,
    const int* __restrict__ bbase, int* __restrict__ deg,
    int* __restrict__ pos, int* __restrict__ ssrc, int N){
  __shared__ int h[1024];
  __shared__ int cur[1024];
  __shared__ int ws[256];
  int b = blockIdx.x, t = threadIdx.x;
  int start = bbase[b], end = bbase[b+1];
  h[t]=0; h[256+t]=0; h[512+t]=0; h[768+t]=0;
  __syncthreads();
  for (int i=start+t; i<end; i+=256) atomicAdd(&h[bk[i]&1023], 1);
  __syncthreads();
  int c0=h[4*t], c1=h[4*t+1], c2=h[4*t+2], c3=h[4*t+3];
  int s = c0+c1+c2+c3;
  ws[t] = s; __syncthreads();
  for (int off=1; off<256; off<<=1){
    int tmp = (t>=off)? ws[t-off]:0;
    __syncthreads();
    ws[t] += tmp;
    __syncthreads();
  }
  int base0 = start + ws[t] - s;
  cur[4*t]   = base0;
  cur[4*t+1] = base0 + c0;
  cur[4*t+2] = base0 + c0 + c1;
  cur[4*t+3] = base0 + c0 + c1 + c2;
  int gk = b*1024 + 4*t;
  int nodeA = (b<<9) + 2*t, nodeB = nodeA + 1;
  if (nodeA < N){
    deg[gk]   = c0; deg[gk+1] = c1;
    pos[gk]   = base0; pos[gk+1] = base0 + c0;
  }
  if (nodeB < N){
    deg[gk+2] = c2; deg[gk+3] = c3;
    pos[gk+2] = base0 + c0 + c1; pos[gk+3] = base0 + c0 + c1 + c2;
  }
  __syncthreads();
  for (int i=start+t; i<end; i+=256){
    uint w = bk[i];
    int p = atomicAdd(&cur[w & 1023], 1);
    ssrc[p] = (int)(w >> 10);
  }
}

// ----------------------- gather (64-ch bf16 features) ---------------------
__global__ __launch_bounds__(256) void k_gather64(
    const ushort* __restrict__ hp, const int* __restrict__ deg,
    const int* __restrict__ pos, const int* __restrict__ ssrc,
    ushort* __restrict__ sn, int N)
{
  int lane = threadIdx.x & 63;
  int wid  = (blockIdx.x*256 + threadIdx.x) >> 6;
  int c4 = lane & 15, eg = lane >> 4;
  int nA = wid*2, nB = nA+1;
  if (nA >= N) return;
  int d0A = deg[2*nA], d1A = deg[2*nA+1];
  int pA  = pos[2*nA];
  int cA  = d0A + d1A;
  int d0B = 0, d1B = 0, pB = 0, cB = 0;
  if (nB < N){ d0B = deg[2*nB]; d1B = deg[2*nB+1]; pB = pos[2*nB]; cB = d0B+d1B; }

  float4 s0A={0,0,0,0}, s1A={0,0,0,0}, s0B={0,0,0,0}, s1B={0,0,0,0};
  int jA = 0, jB = 0;
  while (jA < cA || jB < cB){
    int tA = cA - jA; if (tA > 64) tA = 64;
    int tB = cB - jB; if (tB > 64) tB = 64;
    int svA = (lane < tA) ? ssrc[pA + jA + lane] : 0;
    int svB = (lane < tB) ? ssrc[pB + jB + lane] : 0;
    int mt = tA > tB ? tA : tB;
    for (int e = 0; e < mt; e += 4){
      int idx = e + eg;
      int siA = __shfl(svA, idx), siB = __shfl(svB, idx);
      uint2 wA = {0u,0u}, wB = {0u,0u};
      if (idx < tA) wA = *(const uint2*)(hp + (size_t)siA*64 + c4*4);
      if (idx < tB) wB = *(const uint2*)(hp + (size_t)siB*64 + c4*4);
      float4 fA = bf4cvt(wA), fB = bf4cvt(wB);
      accsel(s0A, s1A, fA, (jA + idx) < d0A);
      accsel(s0B, s1B, fB, (jB + idx) < d0B);
    }
    jA += tA; jB += tB;
  }
  redf4(s0A); redf4(s1A); redf4(s0B); redf4(s1B);
  float i0A = 1.f/(float)(d0A>1?d0A:1), i1A = 1.f/(float)(d1A>1?d1A:1);
  float i0B = 1.f/(float)(d0B>1?d0B:1), i1B = 1.f/(float)(d1B>1?d1B:1);
  s0A.x*=i0A; s0A.y*=i0A; s0A.z*=i0A; s0A.w*=i0A;
  s1A.x*=i1A; s1A.y*=i1A; s1A.z*=i1A; s1A.w*=i1A;
  s0B.x*=i0B; s0B.y*=i0B; s0B.z*=i0B; s0B.w*=i0B;
  s1B.x*=i1B; s1B.y*=i1B; s1B.z*=i1B; s1B.w*=i1B;
  float4 v = (lane < 32) ? ((lane < 16) ? s0A : s1A)
                         : ((lane < 48) ? s0B : s1B);
  int n   = (lane < 32) ? nA : nB;
  int rel = (lane >> 4) & 1;
  if (n < N){
    uint2 pkt; pkt.x = bfpack2(v.x, v.y); pkt.y = bfpack2(v.z, v.w);
    *(uint2*)(sn + (size_t)n*128 + rel*64 + c4*4) = pkt;
  }
}

// ------------------------ gather (8-ch f32 input x) -----------------------
__global__ __launch_bounds__(256) void k_gather8(
    const float* __restrict__ xp, const int* __restrict__ deg,
    const int* __restrict__ pos, const int* __restrict__ ssrc,
    float* __restrict__ sn1, int N)
{
  int lane = threadIdx.x & 63;
  int wid  = (blockIdx.x*256 + threadIdx.x) >> 6;
  int c = lane & 7, eg = lane >> 3;
  int nA = wid*2, nB = nA+1;
  if (nA >= N) return;
  int d0A = deg[2*nA], d1A = deg[2*nA+1];
  int pA  = pos[2*nA];
  int cA  = d0A + d1A;
  int d0B = 0, d1B = 0, pB = 0, cB = 0;
  if (nB < N){ d0B = deg[2*nB]; d1B = deg[2*nB+1]; pB = pos[2*nB]; cB = d0B+d1B; }

  float s0A=0.f, s1A=0.f, s0B=0.f, s1B=0.f;
  int jA = 0, jB = 0;
  while (jA < cA || jB < cB){
    int tA = cA - jA; if (tA > 64) tA = 64;
    int tB = cB - jB; if (tB > 64) tB = 64;
    int svA = (lane < tA) ? ssrc[pA + jA + lane] : 0;
    int svB = (lane < tB) ? ssrc[pB + jB + lane] : 0;
    int mt = tA > tB ? tA : tB;
    for (int e = 0; e < mt; e += 8){
      int idx = e + eg;
      int siA = __shfl(svA, idx), siB = __shfl(svB, idx);
      float vA = 0.f, vB = 0.f;
      if (idx < tA) vA = xp[(size_t)siA*8 + c];
      if (idx < tB) vB = xp[(size_t)siB*8 + c];
      bool r0A = (jA + idx) < d0A, r0B = (jB + idx) < d0B;
      s0A += r0A ? vA : 0.f;  s1A += r0A ? 0.f : vA;
      s0B += r0B ? vB : 0.f;  s1B += r0B ? 0.f : vB;
    }
    jA += tA; jB += tB;
  }
  #pragma unroll
  for (int off=8; off<64; off<<=1){
    s0A += __shfl_xor(s0A, off); s1A += __shfl_xor(s1A, off);
    s0B += __shfl_xor(s0B, off); s1B += __shfl_xor(s1B, off);
  }
  s0A *= 1.f/(float)(d0A>1?d0A:1);  s1A *= 1.f/(float)(d1A>1?d1A:1);
  s0B *= 1.f/(float)(d0B>1?d0B:1);  s1B *= 1.f/(float)(d1B>1?d1B:1);
  if (lane < 32){
    float v = (lane < 16) ? ((lane & 8) ? s1A : s0A)
                          : ((lane & 8) ? s1B : s0B);
    int n = (lane < 16) ? nA : nB;
    if (n < N) sn1[(size_t)n*16 + (lane & 15)] = v;
  }
}

// ----------------------- GEMM layers 2/3 (K=192) --------------------------
#define AST 196
template<int RELU, int OUTBF>
__global__ __launch_bounds__(256) void k_mm192(
    const ushort* __restrict__ sn,   // [N,128] bf16 (rel0|rel1 means)
    const ushort* __restrict__ hp,   // [N,64]  bf16 self
    const float* __restrict__ Wl,    // [128,64]
    const float* __restrict__ rootp, // [64,64]
    const float* __restrict__ bias, void* __restrict__ hout_, int N)
{
  __shared__ float A[64*AST];
  int t = threadIdx.x;
  int nb = blockIdx.x*64;
  #pragma unroll
  for (int k=0;k<4;++k){
    int q = k*256 + t;
    int nl = q>>4, off = q&15;
    int n = nb + nl;
    uint4 w = {0,0,0,0};
    if (n < N) w = *(const uint4*)(sn + (size_t)n*128 + off*8);
    float2 a = bf2cvt(w.x), b = bf2cvt(w.y), c = bf2cvt(w.z), d = bf2cvt(w.w);
    float* dst = &A[nl*AST + off*8];
    float4 lo = {a.x,a.y,b.x,b.y}, hi = {c.x,c.y,d.x,d.y};
    *(float4*)dst = lo; *(float4*)(dst+4) = hi;
  }
  #pragma unroll
  for (int k=0;k<2;++k){
    int q = k*256 + t;
    int nl = q>>3, off = q&7;
    int n = nb + nl;
    uint4 w = {0,0,0,0};
    if (n < N) w = *(const uint4*)(hp + (size_t)n*64 + off*8);
    float2 a = bf2cvt(w.x), b = bf2cvt(w.y), c = bf2cvt(w.z), d = bf2cvt(w.w);
    float* dst = &A[nl*AST + 128 + off*8];
    float4 lo = {a.x,a.y,b.x,b.y}, hi = {c.x,c.y,d.x,d.y};
    *(float4*)dst = lo; *(float4*)(dst+4) = hi;
  }
  __syncthreads();
  int o0 = (t&15)*4, r0 = (t>>4)*4;
  float4 b4 = *(const float4*)(bias+o0);
  float4 a0=b4,a1=b4,a2=b4,a3=b4;
  const float* Ab = &A[r0*AST];
  #pragma unroll 4
  for (int i=0;i<128;++i){
    float4 w = *(const float4*)(Wl + i*64 + o0);
    fma4(a0, Ab[i],       w); fma4(a1, Ab[AST+i],   w);
    fma4(a2, Ab[2*AST+i], w); fma4(a3, Ab[3*AST+i], w);
  }
  #pragma unroll 4
  for (int i=0;i<64;++i){
    float4 w = *(const float4*)(rootp + i*64 + o0);
    fma4(a0, Ab[128+i],       w); fma4(a1, Ab[AST+128+i],   w);
    fma4(a2, Ab[2*AST+128+i], w); fma4(a3, Ab[3*AST+128+i], w);
  }
  float4 accs[4] = {a0,a1,a2,a3};
  #pragma unroll
  for (int q=0;q<4;++q){
    int n = nb + r0 + q;
    if (n < N){
      float4 r = accs[q];
      if (RELU){ r.x=fmaxf(r.x,0.f); r.y=fmaxf(r.y,0.f); r.z=fmaxf(r.z,0.f); r.w=fmaxf(r.w,0.f); }
      if (OUTBF){
        uint2 p; p.x = bfpack2(r.x,r.y); p.y = bfpack2(r.z,r.w);
        *(uint2*)((ushort*)hout_ + (size_t)n*64 + o0) = p;
      } else {
        *(float4*)((float*)hout_ + (size_t)n*64 + o0) = r;
      }
    }
  }
}

// -------------------------- GEMM layer 1 (K=24) ---------------------------
__global__ __launch_bounds__(256) void k_mm24(
    const float* __restrict__ sn1,   // [N,16] f32
    const float* __restrict__ xp,    // [N,8] f32 self
    const float* __restrict__ Wl,    // [16,64]
    const float* __restrict__ rootp, // [8,64]
    const float* __restrict__ bias, ushort* __restrict__ hout, int N)
{
  __shared__ float A[64*25];
  int t = threadIdx.x;
  int nb = blockIdx.x*64;
  #pragma unroll
  for (int k=0;k<4;++k){
    int q = k*256 + t;
    int nl = q>>4, c = q&15;
    int n = nb + nl;
    A[nl*25 + c] = (n < N) ? sn1[(size_t)n*16 + c] : 0.f;
  }
  #pragma unroll
  for (int k=0;k<2;++k){
    int q = k*256 + t;
    int nl = q>>3, c = q&7;
    int n = nb + nl;
    A[nl*25 + 16 + c] = (n < N) ? xp[(size_t)n*8 + c] : 0.f;
  }
  __syncthreads();
  int o0=(t&15)*4, r0=(t>>4)*4;
  float4 b4 = *(const float4*)(bias+o0);
  float4 a0=b4,a1=b4,a2=b4,a3=b4;
  const float* Ab=&A[r0*25];
  #pragma unroll
  for (int i=0;i<16;++i){
    float4 w=*(const float4*)(Wl+i*64+o0);
    fma4(a0,Ab[i],w); fma4(a1,Ab[25+i],w); fma4(a2,Ab[50+i],w); fma4(a3,Ab[75+i],w);
  }
  #pragma unroll
  for (int i=0;i<8;++i){
    float4 w=*(const float4*)(rootp+i*64+o0);
    fma4(a0,Ab[16+i],w); fma4(a1,Ab[41+i],w); fma4(a2,Ab[66+i],w); fma4(a3,Ab[91+i],w);
  }
  float4 accs[4]={a0,a1,a2,a3};
  #pragma unroll
  for (int q=0;q<4;++q){
    int n = nb + r0 + q;
    if (n < N){
      float4 r = accs[q];
      r.x=fmaxf(r.x,0.f); r.y=fmaxf(r.y,0.f); r.z=fmaxf(r.z,0.f); r.w=fmaxf(r.w,0.f);
      uint2 p; p.x = bfpack2(r.x,r.y); p.y = bfpack2(r.z,r.w);
      *(uint2*)(hout + (size_t)n*64 + o0) = p;
    }
  }
}

// ------------------------------- pool + MLP -------------------------------

__device__ __forceinline__ int lowerb(const int* __restrict__ b, int n, int key){
  int lo=0, hi=n;
  while (lo<hi){ int mid=(lo+hi)>>1; if (b[mid]<key) lo=mid+1; else hi=mid; }
  return lo;
}

__global__ __launch_bounds__(256) void k_pool(const float* __restrict__ h,
    const int* __restrict__ batch, float* __restrict__ gp, int N){
  __shared__ float red[256];
  int g=blockIdx.x, t=threadIdx.x;
  int start=lowerb(batch,N,g), end=lowerb(batch,N,g+1);
  int c=t&63, p=t>>6;
  float s=0.f;
  for (int n=start+p; n<end; n+=4) s += h[(size_t)n*64+c];
  red[t]=s; __syncthreads();
  if (t<64) gp[g*64+c] = red[c]+red[64+c]+red[128+c]+red[192+c];
}

// one wave per graph: lane l -> hidden j=l&31, half=l>>5 (channels 32*half..)
__global__ __launch_bounds__(256) void k_clf(const float* __restrict__ gp,
    const float* __restrict__ cW1, const float* __restrict__ cb1,
    const float* __restrict__ cW2, const float* __restrict__ cb2,
    float* __restrict__ out, int G){
  int lane = threadIdx.x & 63;
  int g = (blockIdx.x*256 + threadIdx.x) >> 6;
  if (g >= G) return;
  int j = lane & 31, half = lane >> 5;
  const float* gv = gp + (size_t)g*64 + half*32;
  const float* Wc = cW1 + half*32*32 + j;
  float s = 0.f;
  #pragma unroll 8
  for (int i=0;i<32;++i) s += gv[i] * Wc[i*32];
  s += __shfl_xor(s, 32);                 // merge halves -> full h_j
  s = fmaxf(s + cb1[j], 0.f) * cW2[j];
  s += __shfl_xor(s, 1);  s += __shfl_xor(s, 2);
  s += __shfl_xor(s, 4);  s += __shfl_xor(s, 8);
  s += __shfl_xor(s, 16);                 // sum over j within 32-lane half
  if (lane == 0) out[g] = s + cb2[0];
}

extern "C" void kernel_launch(void* const* d_in, const int* in_sizes, int n_in,
                              void* d_out, int out_size, void* d_ws, size_t ws_size,
                              hipStream_t stream){
  const float* x     = (const float*)d_in[0];
  const int*   ei    = (const int*)d_in[1];
  const int*   et    = (const int*)d_in[2];
  const int*   batch = (const int*)d_in[3];
  const float* W1    = (const float*)d_in[4];
  const float* root1 = (const float*)d_in[5];
  const float* b1    = (const float*)d_in[6];
  const float* W2    = (const float*)d_in[7];
  const float* root2 = (const float*)d_in[8];
  const float* b2    = (const float*)d_in[9];
  const float* W3    = (const float*)d_in[10];
  const float* root3 = (const float*)d_in[11];
  const float* b3    = (const float*)d_in[12];
  const float* cW1   = (const float*)d_in[13];
  const float* cb1   = (const float*)d_in[14];
  const float* cW2   = (const float*)d_in[15];
  const float* cb2   = (const float*)d_in[16];
  float* out = (float*)d_out;
  (void)n_in; (void)ws_size;

  int N = in_sizes[0]/8;      // 100000
  int E = in_sizes[2];        // 3200000
  int G = out_size;           // 256
  int M = 2*N;

  char* w = (char*)d_ws;
  auto alloc=[&](size_t bytes)->char*{ char* p=w; w += (bytes+255)&~(size_t)255; return p; };
  int*    bhist = (int*)alloc(256*4);
  int*    bbase = (int*)alloc(257*4);
  int*    bcur  = (int*)alloc(256*4);
  int*    ssrc  = (int*)alloc((size_t)E*4);
  int*    deg   = (int*)alloc((size_t)M*4);
  int*    pos   = (int*)alloc((size_t)M*4);
  ushort* h1    = (ushort*)alloc((size_t)N*64*2);
  ushort* snU   = (ushort*)alloc((size_t)N*128*2);
  ushort* h2    = (ushort*)alloc((size_t)N*64*2);  // bk aliases this
  float*  gp    = (float*)alloc((size_t)G*64*4);
  uint*   bk    = (uint*)h2;                       // dead before h2 is written
  float*  sn1   = (float*)snU;                     // [N,16] f32, dead after k_mm24
  float*  hf    = (float*)ssrc;                    // [N,64] f32 spans ssrc+deg+pos+h1, all dead at layer-3 GEMM

  hipMemsetAsync(bhist, 0, 256*4, stream);
  int nbE = (E + EPB - 1)/EPB;
  k_count<<<nbE,256,0,stream>>>(ei,bhist,E);
  k_bscan<<<1,256,0,stream>>>(bhist,bbase,bcur);
  k_part <<<nbE,256,0,stream>>>(ei,et,bcur,bk,E);
  k_csr  <<<256,256,0,stream>>>(bk,bbase,deg,pos,ssrc,N);

  int gb = (((N+1)/2) + 3) / 4;     // waves = ceil(N/2), 4 waves/block
  int nbk = (N+63)/64;
  // layer 1
  k_gather8 <<<gb,256,0,stream>>>(x,deg,pos,ssrc,sn1,N);
  k_mm24    <<<nbk,256,0,stream>>>(sn1,x,W1,root1,b1,h1,N);
  // layer 2
  k_gather64<<<gb,256,0,stream>>>(h1,deg,pos,ssrc,snU,N);
  k_mm192<1,1><<<nbk,256,0,stream>>>(snU,h1,W2,root2,b2,h2,N);
  // layer 3
  k_gather64<<<gb,256,0,stream>>>(h2,deg,pos,ssrc,snU,N);
  k_mm192<0,0><<<nbk,256,0,stream>>>(snU,h2,W3,root3,b3,hf,N);
  // pool + head
  k_pool<<<G,256,0,stream>>>(hf,batch,gp,N);
  k_clf<<<(G*64+255)/256,256,0,stream>>>(gp,cW1,cb1,cW2,cb2,out,G);
}